// Round 4
// baseline (533.223 us; speedup 1.0000x reference)
//
#include <hip/hip_runtime.h>
#include <hip/hip_bf16.h>
#include <cstdint>

typedef __bf16 bf16x8 __attribute__((ext_vector_type(8)));
typedef float f32x4 __attribute__((ext_vector_type(4)));

// Q pre-scale: (1/sqrt(768)) * log2(e)  -> attention exp becomes raw exp2
#define SCALE_Q_LOG2E 0.052058770734702875f

// fast exp2 via v_exp_f32 (NOTE: __exp2f collides with glibc math.h macro)
__device__ inline float fast_exp2(float x) { return __builtin_amdgcn_exp2f(x); }

// ---------------------------------------------------------------------------
// prep kernel: 5 weight transposes (fp32->bf16, dst[n][k]=src[k][n]) PLUS
// t-path stage 1 ([2,768]@[768,4608] k-split atomic) in one dispatch.
// 64x64 tiles, float4 loads (16B/lane), uint2 bf16 stores (8B/lane).
// ---------------------------------------------------------------------------
struct PrepArgs {
  const float* src[5];
  __hip_bfloat16* dst[5];
  int K[5], N[5];
  int start[6];           // transpose block ranges; start[5] = total transpose blocks
  const float* tin;       // t input [2,768]
  const float* w_ss1;     // [768,4608]
  float* tacc1;           // [2,4608] (zeroed)
};

__global__ __launch_bounds__(256) void k_prep(PrepArgs pa) {
  __shared__ float tile[64][65];
  int bid = blockIdx.x;
  int tid = threadIdx.x;
  if (bid < pa.start[5]) {
    int i = 0;
#pragma unroll
    for (int j = 1; j < 5; ++j)
      if (bid >= pa.start[j]) i = j;
    int t0 = bid - pa.start[i];
    int N = pa.N[i], K = pa.K[i];
    int ntx = N >> 6;
    int bx = t0 % ntx, by = t0 / ntx;
    const float* src = pa.src[i];
    __hip_bfloat16* dst = pa.dst[i];
    int n0 = bx * 64, k0 = by * 64;
    int c4 = tid & 15, rr = tid >> 4;   // 16 float4-cols x 16 rows per pass
    float4 v[4];
#pragma unroll
    for (int p = 0; p < 4; ++p)
      v[p] = *(const float4*)&src[(size_t)(k0 + rr + 16 * p) * N + n0 + c4 * 4];
#pragma unroll
    for (int p = 0; p < 4; ++p) {
      tile[rr + 16 * p][c4 * 4 + 0] = v[p].x;
      tile[rr + 16 * p][c4 * 4 + 1] = v[p].y;
      tile[rr + 16 * p][c4 * 4 + 2] = v[p].z;
      tile[rr + 16 * p][c4 * 4 + 3] = v[p].w;
    }
    __syncthreads();
    int kg = tid & 15, nl = tid >> 4;
#pragma unroll
    for (int p = 0; p < 4; ++p) {
      int n = nl + 16 * p;
      __hip_bfloat16 t4[4];
#pragma unroll
      for (int j = 0; j < 4; ++j) t4[j] = __float2bfloat16(tile[kg * 4 + j][n]);
      *(uint2*)&dst[(size_t)(n0 + n) * K + k0 + kg * 4] = *(uint2*)t4;
    }
  } else {
    int t0 = bid - pa.start[5];
    int nb = t0 % 18, kb0 = (t0 / 18) * 64;
    int n = nb * 256 + tid;
    float a0 = 0.f, a1 = 0.f;
    for (int k = kb0; k < kb0 + 64; ++k) {
      float w = pa.w_ss1[(size_t)k * 4608 + n];
      a0 += pa.tin[k] * w;
      a1 += pa.tin[768 + k] * w;
    }
    atomicAdd(&pa.tacc1[n], a0);
    atomicAdd(&pa.tacc1[4608 + n], a1);
  }
}

// ---------------------------------------------------------------------------
// t-path stage 2 with inline silu+bias on the input (float2 W loads):
// teacc[b][n] += sum_k silu(tacc1[b][k]+b_ss1[k]) * w_ss2[k][n]
// ---------------------------------------------------------------------------
__global__ void k_tvec2_silu(const float* __restrict__ tacc1, const float* __restrict__ bss1,
                             const float* __restrict__ W, float* __restrict__ teacc) {
  int n2 = blockIdx.x * 256 + threadIdx.x;   // float2 column index, 0..2303
  int kb = blockIdx.y * 64;
  float a0x = 0.f, a0y = 0.f, a1x = 0.f, a1y = 0.f;
  for (int k = kb; k < kb + 64; ++k) {
    float2 w = *(const float2*)&W[(size_t)k * 4608 + n2 * 2];
    float bs = bss1[k];
    float t0 = tacc1[k] + bs;
    float t1 = tacc1[4608 + k] + bs;
    t0 = t0 / (1.f + expf(-t0));
    t1 = t1 / (1.f + expf(-t1));
    a0x += t0 * w.x; a0y += t0 * w.y;
    a1x += t1 * w.x; a1y += t1 * w.y;
  }
  atomicAdd(&teacc[n2 * 2 + 0], a0x);
  atomicAdd(&teacc[n2 * 2 + 1], a0y);
  atomicAdd(&teacc[4608 + n2 * 2 + 0], a1x);
  atomicAdd(&teacc[4608 + n2 * 2 + 1], a1y);
}

// ---------------------------------------------------------------------------
// LayerNorm + adaLN modulate: out_bf16 = (teacc+bss2)[g] * LN(x) + (teacc+bss2)[b]
// ---------------------------------------------------------------------------
__global__ void k_ln_mod(const float* __restrict__ x, const float* __restrict__ lng,
                         const float* __restrict__ lnb, const float* __restrict__ teacc,
                         const float* __restrict__ bss2,
                         int gofs, int bofs, __hip_bfloat16* __restrict__ out) {
  int row = blockIdx.x;          // 0..4095
  int b = row >> 11;             // / 2048
  const float* xr = x + (size_t)row * 768;
  int tid = threadIdx.x;
  float v[3];
  float s = 0.f, sq = 0.f;
#pragma unroll
  for (int i = 0; i < 3; ++i) { v[i] = xr[tid + 256 * i]; s += v[i]; sq += v[i] * v[i]; }
#pragma unroll
  for (int o = 32; o > 0; o >>= 1) { s += __shfl_xor(s, o); sq += __shfl_xor(sq, o); }
  __shared__ float rs[4], rq[4];
  int w = tid >> 6, lane = tid & 63;
  if (lane == 0) { rs[w] = s; rq[w] = sq; }
  __syncthreads();
  s = rs[0] + rs[1] + rs[2] + rs[3];
  sq = rq[0] + rq[1] + rq[2] + rq[3];
  float mu = s * (1.f / 768.f);
  float var = sq * (1.f / 768.f) - mu * mu;
  float rstd = rsqrtf(var + 1e-5f);
  const float* tb = teacc + (size_t)b * 4608;
#pragma unroll
  for (int i = 0; i < 3; ++i) {
    int n = tid + 256 * i;
    float gv = tb[gofs + n] + bss2[gofs + n];
    float bv = tb[bofs + n] + bss2[bofs + n];
    float h = (v[i] - mu) * rstd * lng[n] + lnb[n];
    h = gv * h + bv;
    out[(size_t)row * 768 + n] = __float2bfloat16(h);
  }
}

// ---------------------------------------------------------------------------
// m97-style bf16 MFMA GEMM: C[M,N] = A[M,K] @ Bt[N,K]^T (both [row][k]).
// Tile BM x BN, BK=64, 4 waves (2x2), global_load_lds width=16 staging,
// XOR-swizzled LDS (phys_chunk = logical ^ (row&7)).
// Epilogues: 0=bias->f32, 1=bias+gelu(tanh)->bf16, 2=res+gate*(acc+bias)->f32
//            3=qkv fused: Q scaled ->qkvb, K ->qkvb, V -> VT transposed
//            4=split-K (blockIdx.z = K/4 slice): atomicAdd into pre-zeroed
//              outF; slice 0 also adds res + gate*bias so the total equals
//              res + gate*(sum acc + bias). Fixes the N=768/K=3072 GEMMs'
//              384-block (1.5/CU) occupancy starvation -> 768 blocks.
// ---------------------------------------------------------------------------
template <int BM, int BN, int EPI>
__global__ __launch_bounds__(256)
void k_gemm(const __hip_bfloat16* __restrict__ A,
            const __hip_bfloat16* __restrict__ Bt,
            const float* __restrict__ bias,
            float* __restrict__ outF, __hip_bfloat16* __restrict__ outB,
            __hip_bfloat16* __restrict__ outV,
            const float* __restrict__ res, const float* __restrict__ teacc,
            const float* __restrict__ bss2,
            int gofs, int M, int N, int K) {
  constexpr int MI = BM / 32;
  constexpr int NI = BN / 32;
  __shared__ __align__(16) __hip_bfloat16 As[BM * 64];
  __shared__ __align__(16) __hip_bfloat16 Bs[BN * 64];
  const int tid = threadIdx.x;
  const int w = tid >> 6, lane = tid & 63;
  const int quad = lane >> 4, l16 = lane & 15;
  const int wm = w & 1, wn = w >> 1;
  const int m0 = blockIdx.y * BM, n0 = blockIdx.x * BN;
  const int srow = lane >> 3;
  const int sco = ((lane & 7) ^ srow) * 8;

  f32x4 acc[MI][NI] = {};

  const int kbase = (EPI == 4) ? (int)blockIdx.z * (K >> 2) : 0;
  const int kend  = (EPI == 4) ? kbase + (K >> 2) : K;
  for (int k0 = kbase; k0 < kend; k0 += 64) {
#pragma unroll
    for (int ii = 0; ii < BM / 32; ++ii) {
      int is = w * (BM / 32) + ii;
      const __hip_bfloat16* g = A + (size_t)(m0 + is * 8 + srow) * K + k0 + sco;
      __builtin_amdgcn_global_load_lds(
          (const __attribute__((address_space(1))) void*)g,
          (__attribute__((address_space(3))) void*)&As[is * 512], 16, 0, 0);
    }
#pragma unroll
    for (int ii = 0; ii < BN / 32; ++ii) {
      int is = w * (BN / 32) + ii;
      const __hip_bfloat16* g = Bt + (size_t)(n0 + is * 8 + srow) * K + k0 + sco;
      __builtin_amdgcn_global_load_lds(
          (const __attribute__((address_space(1))) void*)g,
          (__attribute__((address_space(3))) void*)&Bs[is * 512], 16, 0, 0);
    }
    __syncthreads();
#pragma unroll
    for (int ks = 0; ks < 2; ++ks) {
      bf16x8 af[MI], bfv[NI];
#pragma unroll
      for (int i = 0; i < MI; ++i) {
        int row = wm * (BM / 2) + i * 16 + l16;
        int cph = (ks * 4 + quad) ^ (row & 7);
        af[i] = *(const bf16x8*)&As[row * 64 + cph * 8];
      }
#pragma unroll
      for (int j = 0; j < NI; ++j) {
        int row = wn * (BN / 2) + j * 16 + l16;
        int cph = (ks * 4 + quad) ^ (row & 7);
        bfv[j] = *(const bf16x8*)&Bs[row * 64 + cph * 8];
      }
#pragma unroll
      for (int i = 0; i < MI; ++i)
#pragma unroll
        for (int j = 0; j < NI; ++j)
          acc[i][j] = __builtin_amdgcn_mfma_f32_16x16x32_bf16(af[i], bfv[j], acc[i][j], 0, 0, 0);
    }
    __syncthreads();
  }

#pragma unroll
  for (int j = 0; j < NI; ++j) {
    int col = n0 + wn * (BN / 2) + j * 16 + l16;
    float bs = bias[col];
#pragma unroll
    for (int i = 0; i < MI; ++i) {
      int row0 = m0 + wm * (BM / 2) + i * 16 + quad * 4;
      if (EPI == 3 && col >= 1536) {
        // V head: write transposed into VT[(b*12+nh)*64+dl][token], 8B packed
        int d = col - 1536;
        int nh = d >> 6, dl = d & 63;
        int bb = row0 >> 11, tok = row0 & 2047;
        __hip_bfloat16 tmp[4];
#pragma unroll
        for (int r = 0; r < 4; ++r) tmp[r] = __float2bfloat16(acc[i][j][r] + bs);
        *(uint2*)&outV[((size_t)(bb * 12 + nh) * 64 + dl) * 2048 + tok] = *(uint2*)tmp;
      } else {
#pragma unroll
        for (int r = 0; r < 4; ++r) {
          int row = row0 + r;
          float raw = acc[i][j][r];
          float v = raw + bs;
          size_t idx = (size_t)row * N + col;
          if (EPI == 0) {
            outF[idx] = v;
          } else if (EPI == 1) {
            // tanh-approx gelu: v - v/(e+1), e = exp2(2*log2e*0.79788456*(v+0.044715 v^3))
            float v2 = v * v;
            float u = v * (0.79788456080286536f + 0.035677408136300125f * v2);
            float e = fast_exp2(u * 2.8853900817779268f);
            float gl = v - v * __builtin_amdgcn_rcpf(e + 1.f);
            outB[idx] = __float2bfloat16(gl);
          } else if (EPI == 2) {
            float gate = teacc[(size_t)(row >> 11) * 4608 + gofs + col] + bss2[gofs + col];
            outF[idx] = res[idx] + gate * v;
          } else if (EPI == 4) {
            float gate = teacc[(size_t)(row >> 11) * 4608 + gofs + col] + bss2[gofs + col];
            float add = (blockIdx.z == 0) ? (res[idx] + gate * v) : (gate * raw);
            atomicAdd(&outF[idx], add);
          } else {  // EPI==3, Q/K heads
            float vq = (col < 768) ? v * SCALE_Q_LOG2E : v;
            outB[idx] = __float2bfloat16(vq);
          }
        }
      }
    }
  }
}

// ---------------------------------------------------------------------------
// MFMA flash attention (round-3 form: 32KB LDS single-buffer, KV-split x2,
// P aliased into own wave's K region, partial O/l + combine kernel).
// ---------------------------------------------------------------------------
__launch_bounds__(256)
__global__ void k_attn(const __hip_bfloat16* __restrict__ qkvb,
                       const __hip_bfloat16* __restrict__ VT,
                       float* __restrict__ Opart,   // [2][4096][768] f32
                       float* __restrict__ lpart) { // [2][4096][12]  f32
  __shared__ __align__(16) __hip_bfloat16 Ks[128 * 64];  // [s][d], 8-chunk swizzle; doubles as P
  __shared__ __align__(16) __hip_bfloat16 Vs[64 * 128];  // [d][s], 16-chunk swizzle

  const int tid = threadIdx.x;
  const int w = tid >> 6, lane = tid & 63;
  const int quad = lane >> 4, l16 = lane & 15;
  const int qt = blockIdx.x, nh = blockIdx.y;
  const int b = blockIdx.z >> 1, half = blockIdx.z & 1;
  const int bh = b * 12 + nh;
  const int tok0 = b * 2048 + half * 1024;   // global token base for this half

  const int qrow0 = b * 2048 + qt * 64 + w * 16;
  bf16x8 qf[2];
#pragma unroll
  for (int t = 0; t < 2; ++t)
    qf[t] = *(const bf16x8*)(qkvb + (size_t)(qrow0 + l16) * 2304 + nh * 64 + t * 32 + quad * 8);

  bf16x8 ones;
#pragma unroll
  for (int j = 0; j < 8; ++j) ones[j] = (__bf16)1.0f;

  f32x4 o[4] = {};   // col = nf*16+l16, row = quad*4+r
  f32x4 o_l = {};    // row sums (replicated over cols)

  const int srow8 = lane >> 3;               // K staging: 8 rows/instr
  const int sco8 = ((lane & 7) ^ srow8) * 8;
  const int srow4 = lane >> 4;               // V staging: 4 rows/instr

  for (int kt = 0; kt < 8; ++kt) {
    __syncthreads();   // prev tile's PV reads of Vs / P-in-Ks fully retired
    // stage K[kt] -> Ks (wave w writes rows [32w,32w+32) == its own P region)
#pragma unroll
    for (int ii = 0; ii < 4; ++ii) {
      int i = w * 4 + ii;
      const __hip_bfloat16* gk =
          qkvb + (size_t)(tok0 + kt * 128 + i * 8 + srow8) * 2304 + 768 + nh * 64 + sco8;
      __builtin_amdgcn_global_load_lds(
          (const __attribute__((address_space(1))) void*)gk,
          (__attribute__((address_space(3))) void*)&Ks[i * 512], 16, 0, 0);
      int vrow = i * 4 + srow4;
      const __hip_bfloat16* gv =
          VT + (size_t)(bh * 64 + vrow) * 2048 + half * 1024 + kt * 128 +
          (((lane & 15) ^ (vrow & 15)) * 8);
      __builtin_amdgcn_global_load_lds(
          (const __attribute__((address_space(1))) void*)gv,
          (__attribute__((address_space(3))) void*)&Vs[i * 512], 16, 0, 0);
    }
    __syncthreads();   // all K/V staged (implicit vmcnt(0) drain)

    // ---- S = Q K^T : 16 q-rows x 128 s-cols per wave ----
    f32x4 s_acc[8] = {};
    __builtin_amdgcn_s_setprio(1);
#pragma unroll
    for (int t = 0; t < 2; ++t) {
#pragma unroll
      for (int c = 0; c < 8; ++c) {
        int row = c * 16 + l16;
        int cph = (t * 4 + quad) ^ (row & 7);
        bf16x8 kf = *(const bf16x8*)&Ks[row * 64 + cph * 8];
        s_acc[c] = __builtin_amdgcn_mfma_f32_16x16x32_bf16(qf[t], kf, s_acc[c], 0, 0, 0);
      }
    }
    __builtin_amdgcn_s_setprio(0);

    __syncthreads();   // all waves done reading Ks -> safe to write P into it

    // ---- P = exp2(S') -> this wave's own region of Ks (swizzled writes) ----
    __hip_bfloat16* Pb = &Ks[w * 2048];
#pragma unroll
    for (int c = 0; c < 8; ++c) {
      int chunk = c * 2 + (l16 >> 3);
#pragma unroll
      for (int r = 0; r < 4; ++r) {
        float p = fast_exp2(s_acc[c][r]);
        int row = quad * 4 + r;
        int phys = chunk ^ row;
        Pb[row * 128 + phys * 8 + (l16 & 7)] = __float2bfloat16(p);
      }
    }
    // own-wave P write->read ordering only; compiler inserts lgkmcnt. No barrier.

    // ---- O += P V, l += P @ ones ----
    __builtin_amdgcn_s_setprio(1);
#pragma unroll
    for (int t2 = 0; t2 < 4; ++t2) {
      int phys_p = ((t2 * 4 + quad) ^ l16);
      bf16x8 pa = *(const bf16x8*)&Pb[l16 * 128 + phys_p * 8];
#pragma unroll
      for (int nf = 0; nf < 4; ++nf) {
        int row = nf * 16 + l16;
        int cph = (t2 * 4 + quad) ^ (row & 15);
        bf16x8 vf = *(const bf16x8*)&Vs[row * 128 + cph * 8];
        o[nf] = __builtin_amdgcn_mfma_f32_16x16x32_bf16(pa, vf, o[nf], 0, 0, 0);
      }
      o_l = __builtin_amdgcn_mfma_f32_16x16x32_bf16(pa, ones, o_l, 0, 0, 0);
    }
    __builtin_amdgcn_s_setprio(0);
  }

  // ---- epilogue: partial O (f32, pre-division) + partial l ----
  {
    float* op = Opart + (size_t)half * 4096 * 768;
#pragma unroll
    for (int nf = 0; nf < 4; ++nf)
#pragma unroll
      for (int r = 0; r < 4; ++r) {
        int row = qrow0 + quad * 4 + r;
        op[(size_t)row * 768 + nh * 64 + nf * 16 + l16] = o[nf][r];
      }
    // l layout: lpart[(half*4096 + row)*12 + nh]
    if (l16 == 0) {
#pragma unroll
      for (int r = 0; r < 4; ++r) {
        int row = qrow0 + quad * 4 + r;
        lpart[((size_t)half * 4096 + row) * 12 + nh] = o_l[r];
      }
    }
  }
}

// ---------------------------------------------------------------------------
// combine: out[row][nh*64+d] = (O0+O1)[row][nh*64+d] / (l0+l1)[row][nh]
// 4096 blocks x 192 threads; float4 reads, bf16x4 writes.
// ---------------------------------------------------------------------------
__global__ __launch_bounds__(192)
void k_attn_comb(const float* __restrict__ Opart, const float* __restrict__ lpart,
                 __hip_bfloat16* __restrict__ out) {
  int row = blockIdx.x;
  int tid = threadIdx.x;              // 0..191, handles cols [tid*4, tid*4+4)
  int c0 = tid * 4;
  int nh = c0 >> 6;
  float l = lpart[((size_t)row) * 12 + nh] + lpart[((size_t)4096 + row) * 12 + nh];
  float inv = 1.f / l;
  const float* o0 = Opart + (size_t)row * 768 + c0;
  const float* o1 = Opart + (size_t)(4096 + row) * 768 + c0;
  float4 a = *(const float4*)o0;
  float4 bq = *(const float4*)o1;
  __hip_bfloat16 t4[4];
  t4[0] = __float2bfloat16((a.x + bq.x) * inv);
  t4[1] = __float2bfloat16((a.y + bq.y) * inv);
  t4[2] = __float2bfloat16((a.z + bq.z) * inv);
  t4[3] = __float2bfloat16((a.w + bq.w) * inv);
  *(uint2*)&out[(size_t)row * 768 + c0] = *(uint2*)t4;
}

// ---------------------------------------------------------------------------
extern "C" void kernel_launch(void* const* d_in, const int* in_sizes, int n_in,
                              void* d_out, int out_size, void* d_ws, size_t ws_size,
                              hipStream_t stream) {
  const float* x      = (const float*)d_in[0];
  const float* t      = (const float*)d_in[1];
  const float* w_qkv  = (const float*)d_in[2];
  const float* b_qkv  = (const float*)d_in[3];
  const float* w_m1   = (const float*)d_in[4];
  const float* b_m1   = (const float*)d_in[5];
  const float* w_m2   = (const float*)d_in[6];
  const float* b_m2   = (const float*)d_in[7];
  const float* w_ss1  = (const float*)d_in[8];
  const float* b_ss1  = (const float*)d_in[9];
  const float* w_ss2  = (const float*)d_in[10];
  const float* b_ss2  = (const float*)d_in[11];
  const float* ln1_g  = (const float*)d_in[12];
  const float* ln1_b  = (const float*)d_in[13];
  const float* ln2_g  = (const float*)d_in[14];
  const float* ln2_b  = (const float*)d_in[15];
  const float* w_f1   = (const float*)d_in[16];
  const float* b_f1   = (const float*)d_in[17];
  const float* w_f2   = (const float*)d_in[18];
  const float* b_f2   = (const float*)d_in[19];
  float* out = (float*)d_out;

  char* ws = (char*)d_ws;
  size_t off = 0;
  auto alloc = [&](size_t bytes) -> char* {
    off = (off + 255) & ~(size_t)255;
    char* p = ws + off;
    off += bytes;
    return p;
  };
  __hip_bfloat16* wtq  = (__hip_bfloat16*)alloc((size_t)2304 * 768 * 2);
  __hip_bfloat16* wtm1 = (__hip_bfloat16*)alloc((size_t)3072 * 768 * 2);
  __hip_bfloat16* wtm2 = (__hip_bfloat16*)alloc((size_t)768 * 3072 * 2);
  __hip_bfloat16* wtf1 = (__hip_bfloat16*)alloc((size_t)3072 * 768 * 2);
  __hip_bfloat16* wtf2 = (__hip_bfloat16*)alloc((size_t)768 * 3072 * 2);
  float* tacc1 = (float*)alloc(9216 * 4);
  float* teacc = (float*)alloc(9216 * 4);
  __hip_bfloat16* h1   = (__hip_bfloat16*)alloc((size_t)4096 * 768 * 2);   // reused as h2
  __hip_bfloat16* qkvb = (__hip_bfloat16*)alloc((size_t)4096 * 2304 * 2);
  __hip_bfloat16* VT   = (__hip_bfloat16*)alloc((size_t)24 * 64 * 2048 * 2);
  __hip_bfloat16* attn = (__hip_bfloat16*)alloc((size_t)4096 * 768 * 2);
  __hip_bfloat16* act1 = (__hip_bfloat16*)alloc((size_t)4096 * 3072 * 2);  // reused as act2
  float* x1            = (float*)alloc((size_t)4096 * 768 * 4);
  float* Opart         = (float*)alloc((size_t)2 * 4096 * 768 * 4);
  float* lpart         = (float*)alloc((size_t)2 * 4096 * 12 * 4);

  (void)hipMemsetAsync(tacc1, 0, 9216 * 4, stream);
  (void)hipMemsetAsync(teacc, 0, 9216 * 4, stream);
  // split-K targets must start zeroed
  (void)hipMemsetAsync(x1, 0, (size_t)4096 * 768 * 4, stream);
  (void)hipMemsetAsync(out, 0, (size_t)4096 * 768 * 4, stream);

  // prep: 5 weight transposes (64x64 tiles) + t-path stage 1
  PrepArgs pa;
  pa.src[0] = w_qkv; pa.dst[0] = wtq;  pa.K[0] = 768;  pa.N[0] = 2304;
  pa.src[1] = w_m1;  pa.dst[1] = wtm1; pa.K[1] = 768;  pa.N[1] = 3072;
  pa.src[2] = w_m2;  pa.dst[2] = wtm2; pa.K[2] = 3072; pa.N[2] = 768;
  pa.src[3] = w_f1;  pa.dst[3] = wtf1; pa.K[3] = 768;  pa.N[3] = 3072;
  pa.src[4] = w_f2;  pa.dst[4] = wtf2; pa.K[4] = 3072; pa.N[4] = 768;
  pa.start[0] = 0;
  pa.start[1] = pa.start[0] + (2304 / 64) * (768 / 64);
  pa.start[2] = pa.start[1] + (3072 / 64) * (768 / 64);
  pa.start[3] = pa.start[2] + (768 / 64) * (3072 / 64);
  pa.start[4] = pa.start[3] + (3072 / 64) * (768 / 64);
  pa.start[5] = pa.start[4] + (768 / 64) * (3072 / 64);
  pa.tin = t; pa.w_ss1 = w_ss1; pa.tacc1 = tacc1;
  int tvec1_blocks = 18 * 12;  // (4608/256) x (768/64)
  k_prep<<<pa.start[5] + tvec1_blocks, 256, 0, stream>>>(pa);

  // t-path stage 2 (silu+bias inline, float2 loads)
  k_tvec2_silu<<<dim3(4608 / 512, 4608 / 64), 256, 0, stream>>>(tacc1, b_ss1, w_ss2, teacc);

  // block 1: LN1+mod -> qkv GEMM (Q scaled, V transposed to VT) -> attn -> mFFN
  k_ln_mod<<<4096, 256, 0, stream>>>(x, ln1_g, ln1_b, teacc, b_ss2, 0, 768, h1);
  k_gemm<64, 128, 3><<<dim3(2304 / 128, 4096 / 64), 256, 0, stream>>>(
      h1, wtq, b_qkv, nullptr, qkvb, VT, nullptr, nullptr, nullptr, 0, 4096, 2304, 768);
  k_attn<<<dim3(32, 12, 4), 256, 0, stream>>>(qkvb, VT, Opart, lpart);
  k_attn_comb<<<4096, 192, 0, stream>>>(Opart, lpart, attn);
  k_gemm<128, 128, 1><<<dim3(3072 / 128, 4096 / 128), 256, 0, stream>>>(
      attn, wtm1, b_m1, nullptr, act1, nullptr, nullptr, nullptr, nullptr, 0, 4096, 3072, 768);
  // second FFN GEMM: split-K x4 (768 blocks), atomic f32 accumulate into x1
  k_gemm<128, 128, 4><<<dim3(768 / 128, 4096 / 128, 4), 256, 0, stream>>>(
      act1, wtm2, b_m2, x1, nullptr, nullptr, x, teacc, b_ss2, 1536, 4096, 768, 3072);

  // block 2: LN2+mod -> FFN
  k_ln_mod<<<4096, 256, 0, stream>>>(x1, ln2_g, ln2_b, teacc, b_ss2, 2304, 3072, h1);
  k_gemm<128, 128, 1><<<dim3(3072 / 128, 4096 / 128), 256, 0, stream>>>(
      h1, wtf1, b_f1, nullptr, act1, nullptr, nullptr, nullptr, nullptr, 0, 4096, 3072, 768);
  k_gemm<128, 128, 4><<<dim3(768 / 128, 4096 / 128, 4), 256, 0, stream>>>(
      act1, wtf2, b_f2, out, nullptr, nullptr, x1, teacc, b_ss2, 3840, 4096, 768, 3072);
}

// Round 5
// 470.725 us; speedup vs baseline: 1.1328x; 1.1328x over previous
//
#include <hip/hip_runtime.h>
#include <hip/hip_bf16.h>
#include <cstdint>

typedef __bf16 bf16x8 __attribute__((ext_vector_type(8)));
typedef float f32x4 __attribute__((ext_vector_type(4)));

// Q pre-scale: (1/sqrt(768)) * log2(e)  -> attention exp becomes raw exp2
#define SCALE_Q_LOG2E 0.052058770734702875f

// fast exp2 via v_exp_f32 (NOTE: __exp2f collides with glibc math.h macro)
__device__ inline float fast_exp2(float x) { return __builtin_amdgcn_exp2f(x); }

// ---------------------------------------------------------------------------
// prep kernel: 5 weight transposes (fp32->bf16, dst[n][k]=src[k][n]) PLUS
// t-path stage 1 ([2,768]@[768,4608] k-split atomic) in one dispatch.
// 64x64 tiles, float4 loads (16B/lane), uint2 bf16 stores (8B/lane).
// ---------------------------------------------------------------------------
struct PrepArgs {
  const float* src[5];
  __hip_bfloat16* dst[5];
  int K[5], N[5];
  int start[6];           // transpose block ranges; start[5] = total transpose blocks
  const float* tin;       // t input [2,768]
  const float* w_ss1;     // [768,4608]
  float* tacc1;           // [2,4608] (zeroed)
};

__global__ __launch_bounds__(256) void k_prep(PrepArgs pa) {
  __shared__ float tile[64][65];
  int bid = blockIdx.x;
  int tid = threadIdx.x;
  if (bid < pa.start[5]) {
    int i = 0;
#pragma unroll
    for (int j = 1; j < 5; ++j)
      if (bid >= pa.start[j]) i = j;
    int t0 = bid - pa.start[i];
    int N = pa.N[i], K = pa.K[i];
    int ntx = N >> 6;
    int bx = t0 % ntx, by = t0 / ntx;
    const float* src = pa.src[i];
    __hip_bfloat16* dst = pa.dst[i];
    int n0 = bx * 64, k0 = by * 64;
    int c4 = tid & 15, rr = tid >> 4;   // 16 float4-cols x 16 rows per pass
    float4 v[4];
#pragma unroll
    for (int p = 0; p < 4; ++p)
      v[p] = *(const float4*)&src[(size_t)(k0 + rr + 16 * p) * N + n0 + c4 * 4];
#pragma unroll
    for (int p = 0; p < 4; ++p) {
      tile[rr + 16 * p][c4 * 4 + 0] = v[p].x;
      tile[rr + 16 * p][c4 * 4 + 1] = v[p].y;
      tile[rr + 16 * p][c4 * 4 + 2] = v[p].z;
      tile[rr + 16 * p][c4 * 4 + 3] = v[p].w;
    }
    __syncthreads();
    int kg = tid & 15, nl = tid >> 4;
#pragma unroll
    for (int p = 0; p < 4; ++p) {
      int n = nl + 16 * p;
      __hip_bfloat16 t4[4];
#pragma unroll
      for (int j = 0; j < 4; ++j) t4[j] = __float2bfloat16(tile[kg * 4 + j][n]);
      *(uint2*)&dst[(size_t)(n0 + n) * K + k0 + kg * 4] = *(uint2*)t4;
    }
  } else {
    int t0 = bid - pa.start[5];
    int nb = t0 % 18, kb0 = (t0 / 18) * 64;
    int n = nb * 256 + tid;
    float a0 = 0.f, a1 = 0.f;
    for (int k = kb0; k < kb0 + 64; ++k) {
      float w = pa.w_ss1[(size_t)k * 4608 + n];
      a0 += pa.tin[k] * w;
      a1 += pa.tin[768 + k] * w;
    }
    atomicAdd(&pa.tacc1[n], a0);
    atomicAdd(&pa.tacc1[4608 + n], a1);
  }
}

// ---------------------------------------------------------------------------
// t-path stage 2 with inline silu+bias on the input (float2 W loads):
// teacc[b][n] += sum_k silu(tacc1[b][k]+b_ss1[k]) * w_ss2[k][n]
// ---------------------------------------------------------------------------
__global__ void k_tvec2_silu(const float* __restrict__ tacc1, const float* __restrict__ bss1,
                             const float* __restrict__ W, float* __restrict__ teacc) {
  int n2 = blockIdx.x * 256 + threadIdx.x;   // float2 column index, 0..2303
  int kb = blockIdx.y * 64;
  float a0x = 0.f, a0y = 0.f, a1x = 0.f, a1y = 0.f;
  for (int k = kb; k < kb + 64; ++k) {
    float2 w = *(const float2*)&W[(size_t)k * 4608 + n2 * 2];
    float bs = bss1[k];
    float t0 = tacc1[k] + bs;
    float t1 = tacc1[4608 + k] + bs;
    t0 = t0 / (1.f + expf(-t0));
    t1 = t1 / (1.f + expf(-t1));
    a0x += t0 * w.x; a0y += t0 * w.y;
    a1x += t1 * w.x; a1y += t1 * w.y;
  }
  atomicAdd(&teacc[n2 * 2 + 0], a0x);
  atomicAdd(&teacc[n2 * 2 + 1], a0y);
  atomicAdd(&teacc[4608 + n2 * 2 + 0], a1x);
  atomicAdd(&teacc[4608 + n2 * 2 + 1], a1y);
}

// ---------------------------------------------------------------------------
// LayerNorm + adaLN modulate: out_bf16 = (teacc+bss2)[g] * LN(x) + (teacc+bss2)[b]
// ---------------------------------------------------------------------------
__global__ void k_ln_mod(const float* __restrict__ x, const float* __restrict__ lng,
                         const float* __restrict__ lnb, const float* __restrict__ teacc,
                         const float* __restrict__ bss2,
                         int gofs, int bofs, __hip_bfloat16* __restrict__ out) {
  int row = blockIdx.x;          // 0..4095
  int b = row >> 11;             // / 2048
  const float* xr = x + (size_t)row * 768;
  int tid = threadIdx.x;
  float v[3];
  float s = 0.f, sq = 0.f;
#pragma unroll
  for (int i = 0; i < 3; ++i) { v[i] = xr[tid + 256 * i]; s += v[i]; sq += v[i] * v[i]; }
#pragma unroll
  for (int o = 32; o > 0; o >>= 1) { s += __shfl_xor(s, o); sq += __shfl_xor(sq, o); }
  __shared__ float rs[4], rq[4];
  int w = tid >> 6, lane = tid & 63;
  if (lane == 0) { rs[w] = s; rq[w] = sq; }
  __syncthreads();
  s = rs[0] + rs[1] + rs[2] + rs[3];
  sq = rq[0] + rq[1] + rq[2] + rq[3];
  float mu = s * (1.f / 768.f);
  float var = sq * (1.f / 768.f) - mu * mu;
  float rstd = rsqrtf(var + 1e-5f);
  const float* tb = teacc + (size_t)b * 4608;
#pragma unroll
  for (int i = 0; i < 3; ++i) {
    int n = tid + 256 * i;
    float gv = tb[gofs + n] + bss2[gofs + n];
    float bv = tb[bofs + n] + bss2[bofs + n];
    float h = (v[i] - mu) * rstd * lng[n] + lnb[n];
    h = gv * h + bv;
    out[(size_t)row * 768 + n] = __float2bfloat16(h);
  }
}

// ---------------------------------------------------------------------------
// m97-style bf16 MFMA GEMM: C[M,N] = A[M,K] @ Bt[N,K]^T (both [row][k]).
// Tile BM x BN, BK=64, 4 waves (2x2), global_load_lds width=16 staging,
// XOR-swizzled LDS (phys_chunk = logical ^ (row&7)).
// Epilogues: 0=bias->f32, 1=bias+gelu(tanh)->bf16, 2=res+gate*(acc+bias)->f32
//            3=qkv fused: Q scaled ->qkvb, K ->qkvb, V -> VT transposed
// NOTE (r4 lesson): split-K via f32 atomicAdd REGRESSED badly (71.5 us/dispatch,
// 48 MB atomic writes + 93 MB fetch, MfmaUtil 10%). For the N=768/K=3072
// shape use a 64x64 tile instead: doubles grid to 768 blocks (3/CU) at
// IDENTICAL total staged bytes, no atomics.
// ---------------------------------------------------------------------------
template <int BM, int BN, int EPI>
__global__ __launch_bounds__(256)
void k_gemm(const __hip_bfloat16* __restrict__ A,
            const __hip_bfloat16* __restrict__ Bt,
            const float* __restrict__ bias,
            float* __restrict__ outF, __hip_bfloat16* __restrict__ outB,
            __hip_bfloat16* __restrict__ outV,
            const float* __restrict__ res, const float* __restrict__ teacc,
            const float* __restrict__ bss2,
            int gofs, int M, int N, int K) {
  constexpr int MI = BM / 32;
  constexpr int NI = BN / 32;
  __shared__ __align__(16) __hip_bfloat16 As[BM * 64];
  __shared__ __align__(16) __hip_bfloat16 Bs[BN * 64];
  const int tid = threadIdx.x;
  const int w = tid >> 6, lane = tid & 63;
  const int quad = lane >> 4, l16 = lane & 15;
  const int wm = w & 1, wn = w >> 1;
  const int m0 = blockIdx.y * BM, n0 = blockIdx.x * BN;
  const int srow = lane >> 3;
  const int sco = ((lane & 7) ^ srow) * 8;

  f32x4 acc[MI][NI] = {};

  for (int k0 = 0; k0 < K; k0 += 64) {
#pragma unroll
    for (int ii = 0; ii < BM / 32; ++ii) {
      int is = w * (BM / 32) + ii;
      const __hip_bfloat16* g = A + (size_t)(m0 + is * 8 + srow) * K + k0 + sco;
      __builtin_amdgcn_global_load_lds(
          (const __attribute__((address_space(1))) void*)g,
          (__attribute__((address_space(3))) void*)&As[is * 512], 16, 0, 0);
    }
#pragma unroll
    for (int ii = 0; ii < BN / 32; ++ii) {
      int is = w * (BN / 32) + ii;
      const __hip_bfloat16* g = Bt + (size_t)(n0 + is * 8 + srow) * K + k0 + sco;
      __builtin_amdgcn_global_load_lds(
          (const __attribute__((address_space(1))) void*)g,
          (__attribute__((address_space(3))) void*)&Bs[is * 512], 16, 0, 0);
    }
    __syncthreads();
#pragma unroll
    for (int ks = 0; ks < 2; ++ks) {
      bf16x8 af[MI], bfv[NI];
#pragma unroll
      for (int i = 0; i < MI; ++i) {
        int row = wm * (BM / 2) + i * 16 + l16;
        int cph = (ks * 4 + quad) ^ (row & 7);
        af[i] = *(const bf16x8*)&As[row * 64 + cph * 8];
      }
#pragma unroll
      for (int j = 0; j < NI; ++j) {
        int row = wn * (BN / 2) + j * 16 + l16;
        int cph = (ks * 4 + quad) ^ (row & 7);
        bfv[j] = *(const bf16x8*)&Bs[row * 64 + cph * 8];
      }
#pragma unroll
      for (int i = 0; i < MI; ++i)
#pragma unroll
        for (int j = 0; j < NI; ++j)
          acc[i][j] = __builtin_amdgcn_mfma_f32_16x16x32_bf16(af[i], bfv[j], acc[i][j], 0, 0, 0);
    }
    __syncthreads();
  }

#pragma unroll
  for (int j = 0; j < NI; ++j) {
    int col = n0 + wn * (BN / 2) + j * 16 + l16;
    float bs = bias[col];
#pragma unroll
    for (int i = 0; i < MI; ++i) {
      int row0 = m0 + wm * (BM / 2) + i * 16 + quad * 4;
      if (EPI == 3 && col >= 1536) {
        // V head: write transposed into VT[(b*12+nh)*64+dl][token], 8B packed
        int d = col - 1536;
        int nh = d >> 6, dl = d & 63;
        int bb = row0 >> 11, tok = row0 & 2047;
        __hip_bfloat16 tmp[4];
#pragma unroll
        for (int r = 0; r < 4; ++r) tmp[r] = __float2bfloat16(acc[i][j][r] + bs);
        *(uint2*)&outV[((size_t)(bb * 12 + nh) * 64 + dl) * 2048 + tok] = *(uint2*)tmp;
      } else {
#pragma unroll
        for (int r = 0; r < 4; ++r) {
          int row = row0 + r;
          float v = acc[i][j][r] + bs;
          size_t idx = (size_t)row * N + col;
          if (EPI == 0) {
            outF[idx] = v;
          } else if (EPI == 1) {
            // tanh-approx gelu: v - v/(e+1), e = exp2(2*log2e*0.79788456*(v+0.044715 v^3))
            float v2 = v * v;
            float u = v * (0.79788456080286536f + 0.035677408136300125f * v2);
            float e = fast_exp2(u * 2.8853900817779268f);
            float gl = v - v * __builtin_amdgcn_rcpf(e + 1.f);
            outB[idx] = __float2bfloat16(gl);
          } else if (EPI == 2) {
            float gate = teacc[(size_t)(row >> 11) * 4608 + gofs + col] + bss2[gofs + col];
            outF[idx] = res[idx] + gate * v;
          } else {  // EPI==3, Q/K heads
            float vq = (col < 768) ? v * SCALE_Q_LOG2E : v;
            outB[idx] = __float2bfloat16(vq);
          }
        }
      }
    }
  }
}

// ---------------------------------------------------------------------------
// MFMA flash attention (round-3 form: 32KB LDS single-buffer, KV-split x2,
// P aliased into own wave's K region, partial O/l + combine kernel).
// ---------------------------------------------------------------------------
__launch_bounds__(256)
__global__ void k_attn(const __hip_bfloat16* __restrict__ qkvb,
                       const __hip_bfloat16* __restrict__ VT,
                       float* __restrict__ Opart,   // [2][4096][768] f32
                       float* __restrict__ lpart) { // [2][4096][12]  f32
  __shared__ __align__(16) __hip_bfloat16 Ks[128 * 64];  // [s][d], 8-chunk swizzle; doubles as P
  __shared__ __align__(16) __hip_bfloat16 Vs[64 * 128];  // [d][s], 16-chunk swizzle

  const int tid = threadIdx.x;
  const int w = tid >> 6, lane = tid & 63;
  const int quad = lane >> 4, l16 = lane & 15;
  const int qt = blockIdx.x, nh = blockIdx.y;
  const int b = blockIdx.z >> 1, half = blockIdx.z & 1;
  const int bh = b * 12 + nh;
  const int tok0 = b * 2048 + half * 1024;   // global token base for this half

  const int qrow0 = b * 2048 + qt * 64 + w * 16;
  bf16x8 qf[2];
#pragma unroll
  for (int t = 0; t < 2; ++t)
    qf[t] = *(const bf16x8*)(qkvb + (size_t)(qrow0 + l16) * 2304 + nh * 64 + t * 32 + quad * 8);

  bf16x8 ones;
#pragma unroll
  for (int j = 0; j < 8; ++j) ones[j] = (__bf16)1.0f;

  f32x4 o[4] = {};   // col = nf*16+l16, row = quad*4+r
  f32x4 o_l = {};    // row sums (replicated over cols)

  const int srow8 = lane >> 3;               // K staging: 8 rows/instr
  const int sco8 = ((lane & 7) ^ srow8) * 8;
  const int srow4 = lane >> 4;               // V staging: 4 rows/instr

  for (int kt = 0; kt < 8; ++kt) {
    __syncthreads();   // prev tile's PV reads of Vs / P-in-Ks fully retired
    // stage K[kt] -> Ks (wave w writes rows [32w,32w+32) == its own P region)
#pragma unroll
    for (int ii = 0; ii < 4; ++ii) {
      int i = w * 4 + ii;
      const __hip_bfloat16* gk =
          qkvb + (size_t)(tok0 + kt * 128 + i * 8 + srow8) * 2304 + 768 + nh * 64 + sco8;
      __builtin_amdgcn_global_load_lds(
          (const __attribute__((address_space(1))) void*)gk,
          (__attribute__((address_space(3))) void*)&Ks[i * 512], 16, 0, 0);
      int vrow = i * 4 + srow4;
      const __hip_bfloat16* gv =
          VT + (size_t)(bh * 64 + vrow) * 2048 + half * 1024 + kt * 128 +
          (((lane & 15) ^ (vrow & 15)) * 8);
      __builtin_amdgcn_global_load_lds(
          (const __attribute__((address_space(1))) void*)gv,
          (__attribute__((address_space(3))) void*)&Vs[i * 512], 16, 0, 0);
    }
    __syncthreads();   // all K/V staged (implicit vmcnt(0) drain)

    // ---- S = Q K^T : 16 q-rows x 128 s-cols per wave ----
    f32x4 s_acc[8] = {};
    __builtin_amdgcn_s_setprio(1);
#pragma unroll
    for (int t = 0; t < 2; ++t) {
#pragma unroll
      for (int c = 0; c < 8; ++c) {
        int row = c * 16 + l16;
        int cph = (t * 4 + quad) ^ (row & 7);
        bf16x8 kf = *(const bf16x8*)&Ks[row * 64 + cph * 8];
        s_acc[c] = __builtin_amdgcn_mfma_f32_16x16x32_bf16(qf[t], kf, s_acc[c], 0, 0, 0);
      }
    }
    __builtin_amdgcn_s_setprio(0);

    __syncthreads();   // all waves done reading Ks -> safe to write P into it

    // ---- P = exp2(S') -> this wave's own region of Ks (swizzled writes) ----
    __hip_bfloat16* Pb = &Ks[w * 2048];
#pragma unroll
    for (int c = 0; c < 8; ++c) {
      int chunk = c * 2 + (l16 >> 3);
#pragma unroll
      for (int r = 0; r < 4; ++r) {
        float p = fast_exp2(s_acc[c][r]);
        int row = quad * 4 + r;
        int phys = chunk ^ row;
        Pb[row * 128 + phys * 8 + (l16 & 7)] = __float2bfloat16(p);
      }
    }
    // own-wave P write->read ordering only; compiler inserts lgkmcnt. No barrier.

    // ---- O += P V, l += P @ ones ----
    __builtin_amdgcn_s_setprio(1);
#pragma unroll
    for (int t2 = 0; t2 < 4; ++t2) {
      int phys_p = ((t2 * 4 + quad) ^ l16);
      bf16x8 pa = *(const bf16x8*)&Pb[l16 * 128 + phys_p * 8];
#pragma unroll
      for (int nf = 0; nf < 4; ++nf) {
        int row = nf * 16 + l16;
        int cph = (t2 * 4 + quad) ^ (row & 15);
        bf16x8 vf = *(const bf16x8*)&Vs[row * 128 + cph * 8];
        o[nf] = __builtin_amdgcn_mfma_f32_16x16x32_bf16(pa, vf, o[nf], 0, 0, 0);
      }
      o_l = __builtin_amdgcn_mfma_f32_16x16x32_bf16(pa, ones, o_l, 0, 0, 0);
    }
    __builtin_amdgcn_s_setprio(0);
  }

  // ---- epilogue: partial O (f32, pre-division) + partial l ----
  {
    float* op = Opart + (size_t)half * 4096 * 768;
#pragma unroll
    for (int nf = 0; nf < 4; ++nf)
#pragma unroll
      for (int r = 0; r < 4; ++r) {
        int row = qrow0 + quad * 4 + r;
        op[(size_t)row * 768 + nh * 64 + nf * 16 + l16] = o[nf][r];
      }
    // l layout: lpart[(half*4096 + row)*12 + nh]
    if (l16 == 0) {
#pragma unroll
      for (int r = 0; r < 4; ++r) {
        int row = qrow0 + quad * 4 + r;
        lpart[((size_t)half * 4096 + row) * 12 + nh] = o_l[r];
      }
    }
  }
}

// ---------------------------------------------------------------------------
// combine: out[row][nh*64+d] = (O0+O1)[row][nh*64+d] / (l0+l1)[row][nh]
// 4096 blocks x 192 threads; float4 reads, bf16x4 writes.
// ---------------------------------------------------------------------------
__global__ __launch_bounds__(192)
void k_attn_comb(const float* __restrict__ Opart, const float* __restrict__ lpart,
                 __hip_bfloat16* __restrict__ out) {
  int row = blockIdx.x;
  int tid = threadIdx.x;              // 0..191, handles cols [tid*4, tid*4+4)
  int c0 = tid * 4;
  int nh = c0 >> 6;
  float l = lpart[((size_t)row) * 12 + nh] + lpart[((size_t)4096 + row) * 12 + nh];
  float inv = 1.f / l;
  const float* o0 = Opart + (size_t)row * 768 + c0;
  const float* o1 = Opart + (size_t)(4096 + row) * 768 + c0;
  float4 a = *(const float4*)o0;
  float4 bq = *(const float4*)o1;
  __hip_bfloat16 t4[4];
  t4[0] = __float2bfloat16((a.x + bq.x) * inv);
  t4[1] = __float2bfloat16((a.y + bq.y) * inv);
  t4[2] = __float2bfloat16((a.z + bq.z) * inv);
  t4[3] = __float2bfloat16((a.w + bq.w) * inv);
  *(uint2*)&out[(size_t)row * 768 + c0] = *(uint2*)t4;
}

// ---------------------------------------------------------------------------
extern "C" void kernel_launch(void* const* d_in, const int* in_sizes, int n_in,
                              void* d_out, int out_size, void* d_ws, size_t ws_size,
                              hipStream_t stream) {
  const float* x      = (const float*)d_in[0];
  const float* t      = (const float*)d_in[1];
  const float* w_qkv  = (const float*)d_in[2];
  const float* b_qkv  = (const float*)d_in[3];
  const float* w_m1   = (const float*)d_in[4];
  const float* b_m1   = (const float*)d_in[5];
  const float* w_m2   = (const float*)d_in[6];
  const float* b_m2   = (const float*)d_in[7];
  const float* w_ss1  = (const float*)d_in[8];
  const float* b_ss1  = (const float*)d_in[9];
  const float* w_ss2  = (const float*)d_in[10];
  const float* b_ss2  = (const float*)d_in[11];
  const float* ln1_g  = (const float*)d_in[12];
  const float* ln1_b  = (const float*)d_in[13];
  const float* ln2_g  = (const float*)d_in[14];
  const float* ln2_b  = (const float*)d_in[15];
  const float* w_f1   = (const float*)d_in[16];
  const float* b_f1   = (const float*)d_in[17];
  const float* w_f2   = (const float*)d_in[18];
  const float* b_f2   = (const float*)d_in[19];
  float* out = (float*)d_out;

  char* ws = (char*)d_ws;
  size_t off = 0;
  auto alloc = [&](size_t bytes) -> char* {
    off = (off + 255) & ~(size_t)255;
    char* p = ws + off;
    off += bytes;
    return p;
  };
  __hip_bfloat16* wtq  = (__hip_bfloat16*)alloc((size_t)2304 * 768 * 2);
  __hip_bfloat16* wtm1 = (__hip_bfloat16*)alloc((size_t)3072 * 768 * 2);
  __hip_bfloat16* wtm2 = (__hip_bfloat16*)alloc((size_t)768 * 3072 * 2);
  __hip_bfloat16* wtf1 = (__hip_bfloat16*)alloc((size_t)3072 * 768 * 2);
  __hip_bfloat16* wtf2 = (__hip_bfloat16*)alloc((size_t)768 * 3072 * 2);
  float* tacc1 = (float*)alloc(9216 * 4);
  float* teacc = (float*)alloc(9216 * 4);
  __hip_bfloat16* h1   = (__hip_bfloat16*)alloc((size_t)4096 * 768 * 2);   // reused as h2
  __hip_bfloat16* qkvb = (__hip_bfloat16*)alloc((size_t)4096 * 2304 * 2);
  __hip_bfloat16* VT   = (__hip_bfloat16*)alloc((size_t)24 * 64 * 2048 * 2);
  __hip_bfloat16* attn = (__hip_bfloat16*)alloc((size_t)4096 * 768 * 2);
  __hip_bfloat16* act1 = (__hip_bfloat16*)alloc((size_t)4096 * 3072 * 2);  // reused as act2
  float* x1            = (float*)alloc((size_t)4096 * 768 * 4);
  float* Opart         = (float*)alloc((size_t)2 * 4096 * 768 * 4);
  float* lpart         = (float*)alloc((size_t)2 * 4096 * 12 * 4);

  (void)hipMemsetAsync(tacc1, 0, 9216 * 4, stream);
  (void)hipMemsetAsync(teacc, 0, 9216 * 4, stream);

  // prep: 5 weight transposes (64x64 tiles) + t-path stage 1
  PrepArgs pa;
  pa.src[0] = w_qkv; pa.dst[0] = wtq;  pa.K[0] = 768;  pa.N[0] = 2304;
  pa.src[1] = w_m1;  pa.dst[1] = wtm1; pa.K[1] = 768;  pa.N[1] = 3072;
  pa.src[2] = w_m2;  pa.dst[2] = wtm2; pa.K[2] = 3072; pa.N[2] = 768;
  pa.src[3] = w_f1;  pa.dst[3] = wtf1; pa.K[3] = 768;  pa.N[3] = 3072;
  pa.src[4] = w_f2;  pa.dst[4] = wtf2; pa.K[4] = 3072; pa.N[4] = 768;
  pa.start[0] = 0;
  pa.start[1] = pa.start[0] + (2304 / 64) * (768 / 64);
  pa.start[2] = pa.start[1] + (3072 / 64) * (768 / 64);
  pa.start[3] = pa.start[2] + (768 / 64) * (3072 / 64);
  pa.start[4] = pa.start[3] + (3072 / 64) * (768 / 64);
  pa.start[5] = pa.start[4] + (768 / 64) * (3072 / 64);
  pa.tin = t; pa.w_ss1 = w_ss1; pa.tacc1 = tacc1;
  int tvec1_blocks = 18 * 12;  // (4608/256) x (768/64)
  k_prep<<<pa.start[5] + tvec1_blocks, 256, 0, stream>>>(pa);

  // t-path stage 2 (silu+bias inline, float2 loads)
  k_tvec2_silu<<<dim3(4608 / 512, 4608 / 64), 256, 0, stream>>>(tacc1, b_ss1, w_ss2, teacc);

  // block 1: LN1+mod -> qkv GEMM (Q scaled, V transposed to VT) -> attn -> mFFN
  k_ln_mod<<<4096, 256, 0, stream>>>(x, ln1_g, ln1_b, teacc, b_ss2, 0, 768, h1);
  k_gemm<64, 128, 3><<<dim3(2304 / 128, 4096 / 64), 256, 0, stream>>>(
      h1, wtq, b_qkv, nullptr, qkvb, VT, nullptr, nullptr, nullptr, 0, 4096, 2304, 768);
  k_attn<<<dim3(32, 12, 4), 256, 0, stream>>>(qkvb, VT, Opart, lpart);
  k_attn_comb<<<4096, 192, 0, stream>>>(Opart, lpart, attn);
  k_gemm<128, 128, 1><<<dim3(3072 / 128, 4096 / 128), 256, 0, stream>>>(
      attn, wtm1, b_m1, nullptr, act1, nullptr, nullptr, nullptr, nullptr, 0, 4096, 3072, 768);
  // second FFN GEMM: 64x64 tile -> 768 blocks (3/CU), no atomics
  k_gemm<64, 64, 2><<<dim3(768 / 64, 4096 / 64), 256, 0, stream>>>(
      act1, wtm2, b_m2, x1, nullptr, nullptr, x, teacc, b_ss2, 1536, 4096, 768, 3072);

  // block 2: LN2+mod -> FFN
  k_ln_mod<<<4096, 256, 0, stream>>>(x1, ln2_g, ln2_b, teacc, b_ss2, 2304, 3072, h1);
  k_gemm<128, 128, 1><<<dim3(3072 / 128, 4096 / 128), 256, 0, stream>>>(
      h1, wtf1, b_f1, nullptr, act1, nullptr, nullptr, nullptr, nullptr, 0, 4096, 3072, 768);
  k_gemm<64, 64, 2><<<dim3(768 / 64, 4096 / 64), 256, 0, stream>>>(
      act1, wtf2, b_f2, out, nullptr, nullptr, x1, teacc, b_ss2, 3840, 4096, 768, 3072);
}

// Round 6
// 461.577 us; speedup vs baseline: 1.1552x; 1.0198x over previous
//
#include <hip/hip_runtime.h>
#include <hip/hip_bf16.h>
#include <cstdint>

typedef __bf16 bf16x8 __attribute__((ext_vector_type(8)));
typedef float f32x4 __attribute__((ext_vector_type(4)));
typedef float f32x16 __attribute__((ext_vector_type(16)));

// Q pre-scale: (1/sqrt(768)) * log2(e)  -> attention exp becomes raw exp2
#define SCALE_Q_LOG2E 0.052058770734702875f

// fast exp2 via v_exp_f32 (NOTE: __exp2f collides with glibc math.h macro)
__device__ inline float fast_exp2(float x) { return __builtin_amdgcn_exp2f(x); }

// ---------------------------------------------------------------------------
// prep kernel: 5 weight transposes (fp32->bf16, dst[n][k]=src[k][n]) PLUS
// t-path stage 1 ([2,768]@[768,4608] k-split atomic) in one dispatch.
// 64x64 tiles, float4 loads (16B/lane), uint2 bf16 stores (8B/lane).
// ---------------------------------------------------------------------------
struct PrepArgs {
  const float* src[5];
  __hip_bfloat16* dst[5];
  int K[5], N[5];
  int start[6];           // transpose block ranges; start[5] = total transpose blocks
  const float* tin;       // t input [2,768]
  const float* w_ss1;     // [768,4608]
  float* tacc1;           // [2,4608] (zeroed)
};

__global__ __launch_bounds__(256) void k_prep(PrepArgs pa) {
  __shared__ float tile[64][65];
  int bid = blockIdx.x;
  int tid = threadIdx.x;
  if (bid < pa.start[5]) {
    int i = 0;
#pragma unroll
    for (int j = 1; j < 5; ++j)
      if (bid >= pa.start[j]) i = j;
    int t0 = bid - pa.start[i];
    int N = pa.N[i], K = pa.K[i];
    int ntx = N >> 6;
    int bx = t0 % ntx, by = t0 / ntx;
    const float* src = pa.src[i];
    __hip_bfloat16* dst = pa.dst[i];
    int n0 = bx * 64, k0 = by * 64;
    int c4 = tid & 15, rr = tid >> 4;   // 16 float4-cols x 16 rows per pass
    float4 v[4];
#pragma unroll
    for (int p = 0; p < 4; ++p)
      v[p] = *(const float4*)&src[(size_t)(k0 + rr + 16 * p) * N + n0 + c4 * 4];
#pragma unroll
    for (int p = 0; p < 4; ++p) {
      tile[rr + 16 * p][c4 * 4 + 0] = v[p].x;
      tile[rr + 16 * p][c4 * 4 + 1] = v[p].y;
      tile[rr + 16 * p][c4 * 4 + 2] = v[p].z;
      tile[rr + 16 * p][c4 * 4 + 3] = v[p].w;
    }
    __syncthreads();
    int kg = tid & 15, nl = tid >> 4;
#pragma unroll
    for (int p = 0; p < 4; ++p) {
      int n = nl + 16 * p;
      __hip_bfloat16 t4[4];
#pragma unroll
      for (int j = 0; j < 4; ++j) t4[j] = __float2bfloat16(tile[kg * 4 + j][n]);
      *(uint2*)&dst[(size_t)(n0 + n) * K + k0 + kg * 4] = *(uint2*)t4;
    }
  } else {
    int t0 = bid - pa.start[5];
    int nb = t0 % 18, kb0 = (t0 / 18) * 64;
    int n = nb * 256 + tid;
    float a0 = 0.f, a1 = 0.f;
    for (int k = kb0; k < kb0 + 64; ++k) {
      float w = pa.w_ss1[(size_t)k * 4608 + n];
      a0 += pa.tin[k] * w;
      a1 += pa.tin[768 + k] * w;
    }
    atomicAdd(&pa.tacc1[n], a0);
    atomicAdd(&pa.tacc1[4608 + n], a1);
  }
}

// ---------------------------------------------------------------------------
// t-path stage 2 with inline silu+bias on the input (float2 W loads):
// teacc[b][n] += sum_k silu(tacc1[b][k]+b_ss1[k]) * w_ss2[k][n]
// ---------------------------------------------------------------------------
__global__ void k_tvec2_silu(const float* __restrict__ tacc1, const float* __restrict__ bss1,
                             const float* __restrict__ W, float* __restrict__ teacc) {
  int n2 = blockIdx.x * 256 + threadIdx.x;   // float2 column index, 0..2303
  int kb = blockIdx.y * 64;
  float a0x = 0.f, a0y = 0.f, a1x = 0.f, a1y = 0.f;
  for (int k = kb; k < kb + 64; ++k) {
    float2 w = *(const float2*)&W[(size_t)k * 4608 + n2 * 2];
    float bs = bss1[k];
    float t0 = tacc1[k] + bs;
    float t1 = tacc1[4608 + k] + bs;
    t0 = t0 / (1.f + expf(-t0));
    t1 = t1 / (1.f + expf(-t1));
    a0x += t0 * w.x; a0y += t0 * w.y;
    a1x += t1 * w.x; a1y += t1 * w.y;
  }
  atomicAdd(&teacc[n2 * 2 + 0], a0x);
  atomicAdd(&teacc[n2 * 2 + 1], a0y);
  atomicAdd(&teacc[4608 + n2 * 2 + 0], a1x);
  atomicAdd(&teacc[4608 + n2 * 2 + 1], a1y);
}

// ---------------------------------------------------------------------------
// LayerNorm + adaLN modulate: out_bf16 = (teacc+bss2)[g] * LN(x) + (teacc+bss2)[b]
// ---------------------------------------------------------------------------
__global__ void k_ln_mod(const float* __restrict__ x, const float* __restrict__ lng,
                         const float* __restrict__ lnb, const float* __restrict__ teacc,
                         const float* __restrict__ bss2,
                         int gofs, int bofs, __hip_bfloat16* __restrict__ out) {
  int row = blockIdx.x;          // 0..4095
  int b = row >> 11;             // / 2048
  const float* xr = x + (size_t)row * 768;
  int tid = threadIdx.x;
  float v[3];
  float s = 0.f, sq = 0.f;
#pragma unroll
  for (int i = 0; i < 3; ++i) { v[i] = xr[tid + 256 * i]; s += v[i]; sq += v[i] * v[i]; }
#pragma unroll
  for (int o = 32; o > 0; o >>= 1) { s += __shfl_xor(s, o); sq += __shfl_xor(sq, o); }
  __shared__ float rs[4], rq[4];
  int w = tid >> 6, lane = tid & 63;
  if (lane == 0) { rs[w] = s; rq[w] = sq; }
  __syncthreads();
  s = rs[0] + rs[1] + rs[2] + rs[3];
  sq = rq[0] + rq[1] + rq[2] + rq[3];
  float mu = s * (1.f / 768.f);
  float var = sq * (1.f / 768.f) - mu * mu;
  float rstd = rsqrtf(var + 1e-5f);
  const float* tb = teacc + (size_t)b * 4608;
#pragma unroll
  for (int i = 0; i < 3; ++i) {
    int n = tid + 256 * i;
    float gv = tb[gofs + n] + bss2[gofs + n];
    float bv = tb[bofs + n] + bss2[bofs + n];
    float h = (v[i] - mu) * rstd * lng[n] + lnb[n];
    h = gv * h + bv;
    out[(size_t)row * 768 + n] = __float2bfloat16(h);
  }
}

// ---------------------------------------------------------------------------
// m97-style bf16 MFMA GEMM: C[M,N] = A[M,K] @ Bt[N,K]^T (both [row][k]).
// Tile BM x BN, BK=64, 4 waves (2x2), global_load_lds width=16 staging,
// XOR-swizzled LDS (phys_chunk = logical ^ (row&7)).
// Epilogues: 0=bias->f32, 1=bias+gelu(tanh)->bf16, 2=res+gate*(acc+bias)->f32
//            3=qkv fused: Q scaled ->qkvb, K ->qkvb, V -> VT transposed
// ---------------------------------------------------------------------------
template <int BM, int BN, int EPI>
__global__ __launch_bounds__(256)
void k_gemm(const __hip_bfloat16* __restrict__ A,
            const __hip_bfloat16* __restrict__ Bt,
            const float* __restrict__ bias,
            float* __restrict__ outF, __hip_bfloat16* __restrict__ outB,
            __hip_bfloat16* __restrict__ outV,
            const float* __restrict__ res, const float* __restrict__ teacc,
            const float* __restrict__ bss2,
            int gofs, int M, int N, int K) {
  constexpr int MI = BM / 32;
  constexpr int NI = BN / 32;
  __shared__ __align__(16) __hip_bfloat16 As[BM * 64];
  __shared__ __align__(16) __hip_bfloat16 Bs[BN * 64];
  const int tid = threadIdx.x;
  const int w = tid >> 6, lane = tid & 63;
  const int quad = lane >> 4, l16 = lane & 15;
  const int wm = w & 1, wn = w >> 1;
  const int m0 = blockIdx.y * BM, n0 = blockIdx.x * BN;
  const int srow = lane >> 3;
  const int sco = ((lane & 7) ^ srow) * 8;

  f32x4 acc[MI][NI] = {};

  for (int k0 = 0; k0 < K; k0 += 64) {
#pragma unroll
    for (int ii = 0; ii < BM / 32; ++ii) {
      int is = w * (BM / 32) + ii;
      const __hip_bfloat16* g = A + (size_t)(m0 + is * 8 + srow) * K + k0 + sco;
      __builtin_amdgcn_global_load_lds(
          (const __attribute__((address_space(1))) void*)g,
          (__attribute__((address_space(3))) void*)&As[is * 512], 16, 0, 0);
    }
#pragma unroll
    for (int ii = 0; ii < BN / 32; ++ii) {
      int is = w * (BN / 32) + ii;
      const __hip_bfloat16* g = Bt + (size_t)(n0 + is * 8 + srow) * K + k0 + sco;
      __builtin_amdgcn_global_load_lds(
          (const __attribute__((address_space(1))) void*)g,
          (__attribute__((address_space(3))) void*)&Bs[is * 512], 16, 0, 0);
    }
    __syncthreads();
#pragma unroll
    for (int ks = 0; ks < 2; ++ks) {
      bf16x8 af[MI], bfv[NI];
#pragma unroll
      for (int i = 0; i < MI; ++i) {
        int row = wm * (BM / 2) + i * 16 + l16;
        int cph = (ks * 4 + quad) ^ (row & 7);
        af[i] = *(const bf16x8*)&As[row * 64 + cph * 8];
      }
#pragma unroll
      for (int j = 0; j < NI; ++j) {
        int row = wn * (BN / 2) + j * 16 + l16;
        int cph = (ks * 4 + quad) ^ (row & 7);
        bfv[j] = *(const bf16x8*)&Bs[row * 64 + cph * 8];
      }
#pragma unroll
      for (int i = 0; i < MI; ++i)
#pragma unroll
        for (int j = 0; j < NI; ++j)
          acc[i][j] = __builtin_amdgcn_mfma_f32_16x16x32_bf16(af[i], bfv[j], acc[i][j], 0, 0, 0);
    }
    __syncthreads();
  }

#pragma unroll
  for (int j = 0; j < NI; ++j) {
    int col = n0 + wn * (BN / 2) + j * 16 + l16;
    float bs = bias[col];
#pragma unroll
    for (int i = 0; i < MI; ++i) {
      int row0 = m0 + wm * (BM / 2) + i * 16 + quad * 4;
      if (EPI == 3 && col >= 1536) {
        // V head: write transposed into VT[(b*12+nh)*64+dl][token], 8B packed
        int d = col - 1536;
        int nh = d >> 6, dl = d & 63;
        int bb = row0 >> 11, tok = row0 & 2047;
        __hip_bfloat16 tmp[4];
#pragma unroll
        for (int r = 0; r < 4; ++r) tmp[r] = __float2bfloat16(acc[i][j][r] + bs);
        *(uint2*)&outV[((size_t)(bb * 12 + nh) * 64 + dl) * 2048 + tok] = *(uint2*)tmp;
      } else {
#pragma unroll
        for (int r = 0; r < 4; ++r) {
          int row = row0 + r;
          float v = acc[i][j][r] + bs;
          size_t idx = (size_t)row * N + col;
          if (EPI == 0) {
            outF[idx] = v;
          } else if (EPI == 1) {
            // tanh-approx gelu: v - v/(e+1), e = exp2(2*log2e*0.79788456*(v+0.044715 v^3))
            float v2 = v * v;
            float u = v * (0.79788456080286536f + 0.035677408136300125f * v2);
            float e = fast_exp2(u * 2.8853900817779268f);
            float gl = v - v * __builtin_amdgcn_rcpf(e + 1.f);
            outB[idx] = __float2bfloat16(gl);
          } else if (EPI == 2) {
            float gate = teacc[(size_t)(row >> 11) * 4608 + gofs + col] + bss2[gofs + col];
            outF[idx] = res[idx] + gate * v;
          } else {  // EPI==3, Q/K heads
            float vq = (col < 768) ? v * SCALE_Q_LOG2E : v;
            outB[idx] = __float2bfloat16(vq);
          }
        }
      }
    }
  }
}

// ---------------------------------------------------------------------------
// MFMA flash attention — round-6: in-register softmax via swapped QK^T
// (T12 port of the guide's m214 recipe, adapted to D=64 / 16x16 grid).
//  * 32x32x16 MFMA. QK^T computed SWAPPED: S^T = mfma(K-frag, Q-frag), so
//    each lane holds P[tok...] for ONE q-column (q = lane&31) in registers.
//  * P -> PV A-fragments fully in-register: v_cvt_pk_bf16_f32 pairs +
//    v_permlane32_swap_b32 (frag slice = [w0,w1,w2,w3] after swaps
//    (w0,w2),(w1,w3) — derived from C-layout crow=(r&3)+8(r>>2)+4hi).
//    No P LDS round-trip, 2 barriers/tile instead of 3.
//  * l = row-sum of p in VALU + one shfl_xor(32)  (replaces 4 MFMA/tile).
//  * 4 warps x 32 q-rows = 128 q/block; KVBLK=128; KV-split x2 kept
//    (grid 16x12x4 = 768 blocks = 3/CU even). LDS 32KB (Ks 16K + Vs 16K).
//  * K/V staged via swizzled global_load_lds exactly as before.
// ---------------------------------------------------------------------------
__launch_bounds__(256)
__global__ void k_attn(const __hip_bfloat16* __restrict__ qkvb,
                       const __hip_bfloat16* __restrict__ VT,
                       float* __restrict__ Opart,   // [2][4096][768] f32
                       float* __restrict__ lpart) { // [2][4096][12]  f32
  __shared__ __align__(16) __hip_bfloat16 Ks[128 * 64];  // [tok][d], 8-chunk xor swizzle
  __shared__ __align__(16) __hip_bfloat16 Vs[64 * 128];  // [d][tok], 16-chunk xor swizzle

  const int tid = threadIdx.x;
  const int w = tid >> 6, lane = tid & 63;
  const int l32 = lane & 31, hi = lane >> 5;
  const int qt = blockIdx.x, nh = blockIdx.y;
  const int b = blockIdx.z >> 1, half = blockIdx.z & 1;
  const int bh = b * 12 + nh;

  const int qrow0 = b * 2048 + qt * 128 + w * 32;   // this warp's 32 q-rows
  // Q fragments (B-operand): lane holds Q[q=l32][d = dg*16 + hi*8 + j]
  bf16x8 qf[4];
#pragma unroll
  for (int dg = 0; dg < 4; ++dg)
    qf[dg] = *(const bf16x8*)(qkvb + (size_t)(qrow0 + l32) * 2304 + nh * 64 + dg * 16 + hi * 8);

  f32x16 o0 = {}, o1 = {};   // O accum: col d = dh*32 + l32, row q = (r&3)+8(r>>2)+4hi
  float lsum = 0.f;

  const int krow = lane >> 3;                       // K staging: 8 tok-rows/instr
  const int kco = ((lane & 7) ^ krow) * 8;          // pre-swizzled source chunk

  for (int kt = 0; kt < 8; ++kt) {
    const int tok0 = b * 2048 + half * 1024 + kt * 128;
    __syncthreads();   // prev tile's LDS reads retired
#pragma unroll
    for (int ii = 0; ii < 4; ++ii) {
      int i = w * 4 + ii;
      // K: tok-rows i*8 + (lane>>3), d-chunk swizzled by tok&7
      const __hip_bfloat16* gk =
          qkvb + (size_t)(tok0 + i * 8 + krow) * 2304 + 768 + nh * 64 + kco;
      __builtin_amdgcn_global_load_lds(
          (const __attribute__((address_space(1))) void*)gk,
          (__attribute__((address_space(3))) void*)&Ks[i * 512], 16, 0, 0);
      // V: d-rows i*4 + (lane>>4), tok-chunk swizzled by d&15
      int vd = i * 4 + (lane >> 4);
      const __hip_bfloat16* gv =
          VT + (size_t)(bh * 64 + vd) * 2048 + half * 1024 + kt * 128 +
          (((lane & 15) ^ (vd & 15)) * 8);
      __builtin_amdgcn_global_load_lds(
          (const __attribute__((address_space(1))) void*)gv,
          (__attribute__((address_space(3))) void*)&Vs[i * 512], 16, 0, 0);
    }
    __syncthreads();   // all K/V staged

#pragma unroll
    for (int g2 = 0; g2 < 4; ++g2) {   // 32-token groups within the 128-tile
      // ---- S^T = K Q^T : lane gets P-row slice for q = l32 ----
      f32x16 s = {};
      __builtin_amdgcn_s_setprio(1);
#pragma unroll
      for (int dg = 0; dg < 4; ++dg) {
        int tok = g2 * 32 + l32;
        int phys = (dg * 2 + hi) ^ (tok & 7);
        bf16x8 kf = *(const bf16x8*)&Ks[tok * 64 + phys * 8];
        s = __builtin_amdgcn_mfma_f32_32x32x16_bf16(kf, qf[dg], s, 0, 0, 0);
      }
      __builtin_amdgcn_s_setprio(0);

      // ---- P = exp2(S), row-sum, pack to PV A-frags in-register ----
      float p[16];
#pragma unroll
      for (int r = 0; r < 16; ++r) { p[r] = fast_exp2(s[r]); lsum += p[r]; }
      uint32_t wd[8];
#pragma unroll
      for (int i2 = 0; i2 < 8; ++i2)
        asm("v_cvt_pk_bf16_f32 %0, %1, %2" : "=v"(wd[i2]) : "v"(p[2 * i2]), "v"(p[2 * i2 + 1]));
      asm("v_permlane32_swap_b32 %0, %1" : "+v"(wd[0]), "+v"(wd[2]));
      asm("v_permlane32_swap_b32 %0, %1" : "+v"(wd[1]), "+v"(wd[3]));
      asm("v_permlane32_swap_b32 %0, %1" : "+v"(wd[4]), "+v"(wd[6]));
      asm("v_permlane32_swap_b32 %0, %1" : "+v"(wd[5]), "+v"(wd[7]));

      // ---- O += P V over the two 16-token slices of this group ----
      __builtin_amdgcn_s_setprio(1);
#pragma unroll
      for (int s01 = 0; s01 < 2; ++s01) {
        union { uint32_t u[4]; bf16x8 v; } fr;
        fr.u[0] = wd[s01 * 4 + 0]; fr.u[1] = wd[s01 * 4 + 1];
        fr.u[2] = wd[s01 * 4 + 2]; fr.u[3] = wd[s01 * 4 + 3];
        int ks = g2 * 2 + s01;
#pragma unroll
        for (int dh = 0; dh < 2; ++dh) {
          int row = dh * 32 + l32;
          int phys = (ks * 2 + hi) ^ (row & 15);
          bf16x8 vf = *(const bf16x8*)&Vs[row * 128 + phys * 8];
          if (dh == 0) o0 = __builtin_amdgcn_mfma_f32_32x32x16_bf16(fr.v, vf, o0, 0, 0, 0);
          else         o1 = __builtin_amdgcn_mfma_f32_32x32x16_bf16(fr.v, vf, o1, 0, 0, 0);
        }
      }
      __builtin_amdgcn_s_setprio(0);
    }
  }

  // ---- epilogue: partial O (f32, pre-division) + partial l ----
  lsum += __shfl_xor(lsum, 32);   // combine hi/lo token halves for q = l32
  {
    float* op = Opart + (size_t)half * 4096 * 768;
#pragma unroll
    for (int r = 0; r < 16; ++r) {
      int q = (r & 3) + 8 * (r >> 2) + 4 * hi;
      size_t rowofs = (size_t)(qrow0 + q) * 768 + nh * 64;
      op[rowofs + l32]      = o0[r];
      op[rowofs + 32 + l32] = o1[r];
    }
    if (lane < 32)
      lpart[((size_t)half * 4096 + qrow0 + l32) * 12 + nh] = lsum;
  }
}

// ---------------------------------------------------------------------------
// combine: out[row][nh*64+d] = (O0+O1)[row][nh*64+d] / (l0+l1)[row][nh]
// 4096 blocks x 192 threads; float4 reads, bf16x4 writes.
// ---------------------------------------------------------------------------
__global__ __launch_bounds__(192)
void k_attn_comb(const float* __restrict__ Opart, const float* __restrict__ lpart,
                 __hip_bfloat16* __restrict__ out) {
  int row = blockIdx.x;
  int tid = threadIdx.x;              // 0..191, handles cols [tid*4, tid*4+4)
  int c0 = tid * 4;
  int nh = c0 >> 6;
  float l = lpart[((size_t)row) * 12 + nh] + lpart[((size_t)4096 + row) * 12 + nh];
  float inv = 1.f / l;
  const float* o0 = Opart + (size_t)row * 768 + c0;
  const float* o1 = Opart + (size_t)(4096 + row) * 768 + c0;
  float4 a = *(const float4*)o0;
  float4 bq = *(const float4*)o1;
  __hip_bfloat16 t4[4];
  t4[0] = __float2bfloat16((a.x + bq.x) * inv);
  t4[1] = __float2bfloat16((a.y + bq.y) * inv);
  t4[2] = __float2bfloat16((a.z + bq.z) * inv);
  t4[3] = __float2bfloat16((a.w + bq.w) * inv);
  *(uint2*)&out[(size_t)row * 768 + c0] = *(uint2*)t4;
}

// ---------------------------------------------------------------------------
extern "C" void kernel_launch(void* const* d_in, const int* in_sizes, int n_in,
                              void* d_out, int out_size, void* d_ws, size_t ws_size,
                              hipStream_t stream) {
  const float* x      = (const float*)d_in[0];
  const float* t      = (const float*)d_in[1];
  const float* w_qkv  = (const float*)d_in[2];
  const float* b_qkv  = (const float*)d_in[3];
  const float* w_m1   = (const float*)d_in[4];
  const float* b_m1   = (const float*)d_in[5];
  const float* w_m2   = (const float*)d_in[6];
  const float* b_m2   = (const float*)d_in[7];
  const float* w_ss1  = (const float*)d_in[8];
  const float* b_ss1  = (const float*)d_in[9];
  const float* w_ss2  = (const float*)d_in[10];
  const float* b_ss2  = (const float*)d_in[11];
  const float* ln1_g  = (const float*)d_in[12];
  const float* ln1_b  = (const float*)d_in[13];
  const float* ln2_g  = (const float*)d_in[14];
  const float* ln2_b  = (const float*)d_in[15];
  const float* w_f1   = (const float*)d_in[16];
  const float* b_f1   = (const float*)d_in[17];
  const float* w_f2   = (const float*)d_in[18];
  const float* b_f2   = (const float*)d_in[19];
  float* out = (float*)d_out;

  char* ws = (char*)d_ws;
  size_t off = 0;
  auto alloc = [&](size_t bytes) -> char* {
    off = (off + 255) & ~(size_t)255;
    char* p = ws + off;
    off += bytes;
    return p;
  };
  __hip_bfloat16* wtq  = (__hip_bfloat16*)alloc((size_t)2304 * 768 * 2);
  __hip_bfloat16* wtm1 = (__hip_bfloat16*)alloc((size_t)3072 * 768 * 2);
  __hip_bfloat16* wtm2 = (__hip_bfloat16*)alloc((size_t)768 * 3072 * 2);
  __hip_bfloat16* wtf1 = (__hip_bfloat16*)alloc((size_t)3072 * 768 * 2);
  __hip_bfloat16* wtf2 = (__hip_bfloat16*)alloc((size_t)768 * 3072 * 2);
  float* tacc1 = (float*)alloc(9216 * 4);
  float* teacc = (float*)alloc(9216 * 4);
  __hip_bfloat16* h1   = (__hip_bfloat16*)alloc((size_t)4096 * 768 * 2);   // reused as h2
  __hip_bfloat16* qkvb = (__hip_bfloat16*)alloc((size_t)4096 * 2304 * 2);
  __hip_bfloat16* VT   = (__hip_bfloat16*)alloc((size_t)24 * 64 * 2048 * 2);
  __hip_bfloat16* attn = (__hip_bfloat16*)alloc((size_t)4096 * 768 * 2);
  __hip_bfloat16* act1 = (__hip_bfloat16*)alloc((size_t)4096 * 3072 * 2);  // reused as act2
  float* x1            = (float*)alloc((size_t)4096 * 768 * 4);
  float* Opart         = (float*)alloc((size_t)2 * 4096 * 768 * 4);
  float* lpart         = (float*)alloc((size_t)2 * 4096 * 12 * 4);

  (void)hipMemsetAsync(tacc1, 0, 9216 * 4, stream);
  (void)hipMemsetAsync(teacc, 0, 9216 * 4, stream);

  // prep: 5 weight transposes (64x64 tiles) + t-path stage 1
  PrepArgs pa;
  pa.src[0] = w_qkv; pa.dst[0] = wtq;  pa.K[0] = 768;  pa.N[0] = 2304;
  pa.src[1] = w_m1;  pa.dst[1] = wtm1; pa.K[1] = 768;  pa.N[1] = 3072;
  pa.src[2] = w_m2;  pa.dst[2] = wtm2; pa.K[2] = 3072; pa.N[2] = 768;
  pa.src[3] = w_f1;  pa.dst[3] = wtf1; pa.K[3] = 768;  pa.N[3] = 3072;
  pa.src[4] = w_f2;  pa.dst[4] = wtf2; pa.K[4] = 3072; pa.N[4] = 768;
  pa.start[0] = 0;
  pa.start[1] = pa.start[0] + (2304 / 64) * (768 / 64);
  pa.start[2] = pa.start[1] + (3072 / 64) * (768 / 64);
  pa.start[3] = pa.start[2] + (768 / 64) * (3072 / 64);
  pa.start[4] = pa.start[3] + (3072 / 64) * (768 / 64);
  pa.start[5] = pa.start[4] + (768 / 64) * (3072 / 64);
  pa.tin = t; pa.w_ss1 = w_ss1; pa.tacc1 = tacc1;
  int tvec1_blocks = 18 * 12;  // (4608/256) x (768/64)
  k_prep<<<pa.start[5] + tvec1_blocks, 256, 0, stream>>>(pa);

  // t-path stage 2 (silu+bias inline, float2 loads)
  k_tvec2_silu<<<dim3(4608 / 512, 4608 / 64), 256, 0, stream>>>(tacc1, b_ss1, w_ss2, teacc);

  // block 1: LN1+mod -> qkv GEMM (Q scaled, V transposed to VT) -> attn -> mFFN
  k_ln_mod<<<4096, 256, 0, stream>>>(x, ln1_g, ln1_b, teacc, b_ss2, 0, 768, h1);
  k_gemm<64, 128, 3><<<dim3(2304 / 128, 4096 / 64), 256, 0, stream>>>(
      h1, wtq, b_qkv, nullptr, qkvb, VT, nullptr, nullptr, nullptr, 0, 4096, 2304, 768);
  k_attn<<<dim3(16, 12, 4), 256, 0, stream>>>(qkvb, VT, Opart, lpart);
  k_attn_comb<<<4096, 192, 0, stream>>>(Opart, lpart, attn);
  k_gemm<128, 128, 1><<<dim3(3072 / 128, 4096 / 128), 256, 0, stream>>>(
      attn, wtm1, b_m1, nullptr, act1, nullptr, nullptr, nullptr, nullptr, 0, 4096, 3072, 768);
  k_gemm<64, 64, 2><<<dim3(768 / 64, 4096 / 64), 256, 0, stream>>>(
      act1, wtm2, b_m2, x1, nullptr, nullptr, x, teacc, b_ss2, 1536, 4096, 768, 3072);

  // block 2: LN2+mod -> FFN
  k_ln_mod<<<4096, 256, 0, stream>>>(x1, ln2_g, ln2_b, teacc, b_ss2, 2304, 3072, h1);
  k_gemm<128, 128, 1><<<dim3(3072 / 128, 4096 / 128), 256, 0, stream>>>(
      h1, wtf1, b_f1, nullptr, act1, nullptr, nullptr, nullptr, nullptr, 0, 4096, 3072, 768);
  k_gemm<64, 64, 2><<<dim3(768 / 64, 4096 / 64), 256, 0, stream>>>(
      act1, wtf2, b_f2, out, nullptr, nullptr, x1, teacc, b_ss2, 3840, 4096, 768, 3072);
}

// Round 7
// 427.183 us; speedup vs baseline: 1.2482x; 1.0805x over previous
//
#include <hip/hip_runtime.h>
#include <hip/hip_bf16.h>
#include <cstdint>

typedef __bf16 bf16x8 __attribute__((ext_vector_type(8)));
typedef float f32x4 __attribute__((ext_vector_type(4)));
typedef float f32x16 __attribute__((ext_vector_type(16)));

// Q pre-scale: (1/sqrt(768)) * log2(e)  -> attention exp becomes raw exp2
#define SCALE_Q_LOG2E 0.052058770734702875f

// fast exp2 via v_exp_f32 (NOTE: __exp2f collides with glibc math.h macro)
__device__ inline float fast_exp2(float x) { return __builtin_amdgcn_exp2f(x); }

// ---------------------------------------------------------------------------
// prep kernel: 5 weight transposes (fp32->bf16, dst[n][k]=src[k][n]) PLUS
// t-path stage 1 ([2,768]@[768,4608] k-split atomic) in one dispatch.
// r7: t-path stage-1 was the hidden ~45 us straggler (216 blocks, unstaged
// loads). Now: k-split 16 -> 864 blocks, 16 loads explicitly staged into
// registers before the FMA chain.
// ---------------------------------------------------------------------------
struct PrepArgs {
  const float* src[5];
  __hip_bfloat16* dst[5];
  int K[5], N[5];
  int start[6];           // transpose block ranges; start[5] = total transpose blocks
  const float* tin;       // t input [2,768]
  const float* w_ss1;     // [768,4608]
  float* tacc1;           // [2,4608] (zeroed)
};

__global__ __launch_bounds__(256) void k_prep(PrepArgs pa) {
  __shared__ float tile[64][65];
  int bid = blockIdx.x;
  int tid = threadIdx.x;
  if (bid < pa.start[5]) {
    int i = 0;
#pragma unroll
    for (int j = 1; j < 5; ++j)
      if (bid >= pa.start[j]) i = j;
    int t0 = bid - pa.start[i];
    int N = pa.N[i], K = pa.K[i];
    int ntx = N >> 6;
    int bx = t0 % ntx, by = t0 / ntx;
    const float* src = pa.src[i];
    __hip_bfloat16* dst = pa.dst[i];
    int n0 = bx * 64, k0 = by * 64;
    int c4 = tid & 15, rr = tid >> 4;   // 16 float4-cols x 16 rows per pass
    float4 v[4];
#pragma unroll
    for (int p = 0; p < 4; ++p)
      v[p] = *(const float4*)&src[(size_t)(k0 + rr + 16 * p) * N + n0 + c4 * 4];
#pragma unroll
    for (int p = 0; p < 4; ++p) {
      tile[rr + 16 * p][c4 * 4 + 0] = v[p].x;
      tile[rr + 16 * p][c4 * 4 + 1] = v[p].y;
      tile[rr + 16 * p][c4 * 4 + 2] = v[p].z;
      tile[rr + 16 * p][c4 * 4 + 3] = v[p].w;
    }
    __syncthreads();
    int kg = tid & 15, nl = tid >> 4;
#pragma unroll
    for (int p = 0; p < 4; ++p) {
      int n = nl + 16 * p;
      __hip_bfloat16 t4[4];
#pragma unroll
      for (int j = 0; j < 4; ++j) t4[j] = __float2bfloat16(tile[kg * 4 + j][n]);
      *(uint2*)&dst[(size_t)(n0 + n) * K + k0 + kg * 4] = *(uint2*)t4;
    }
  } else {
    // t-path stage 1: 18 n-blocks x 48 k-blocks (16 k each), staged loads.
    int t0 = bid - pa.start[5];
    int nb = t0 % 18, kb0 = (t0 / 18) * 16;
    int n = nb * 256 + tid;
    float wv[16];
#pragma unroll
    for (int kk = 0; kk < 16; ++kk)
      wv[kk] = pa.w_ss1[(size_t)(kb0 + kk) * 4608 + n];
    float a0 = 0.f, a1 = 0.f;
#pragma unroll
    for (int kk = 0; kk < 16; ++kk) {
      a0 += pa.tin[kb0 + kk] * wv[kk];
      a1 += pa.tin[768 + kb0 + kk] * wv[kk];
    }
    atomicAdd(&pa.tacc1[n], a0);
    atomicAdd(&pa.tacc1[4608 + n], a1);
  }
}

// ---------------------------------------------------------------------------
// t-path stage 2 with inline silu+bias on the input:
// teacc[b][n] += sum_k silu(tacc1[b][k]+b_ss1[k]) * w_ss2[k][n]
// r7: 4 chunks x 16 float2 W loads explicitly staged into registers
// (was an interleaved load/FMA loop -> poor pipelining, est ~45 us hidden).
// ---------------------------------------------------------------------------
__global__ void k_tvec2_silu(const float* __restrict__ tacc1, const float* __restrict__ bss1,
                             const float* __restrict__ W, float* __restrict__ teacc) {
  int n2 = blockIdx.x * 256 + threadIdx.x;   // float2 column index, 0..2303
  int kb = blockIdx.y * 64;
  float a0x = 0.f, a0y = 0.f, a1x = 0.f, a1y = 0.f;
#pragma unroll 1
  for (int kc = 0; kc < 4; ++kc) {
    int k0 = kb + kc * 16;
    float2 wv[16];
#pragma unroll
    for (int kk = 0; kk < 16; ++kk)
      wv[kk] = *(const float2*)&W[(size_t)(k0 + kk) * 4608 + n2 * 2];
#pragma unroll
    for (int kk = 0; kk < 16; ++kk) {
      int k = k0 + kk;
      float bs = bss1[k];
      float t0 = tacc1[k] + bs;
      float t1 = tacc1[4608 + k] + bs;
      t0 = t0 / (1.f + expf(-t0));
      t1 = t1 / (1.f + expf(-t1));
      a0x += t0 * wv[kk].x; a0y += t0 * wv[kk].y;
      a1x += t1 * wv[kk].x; a1y += t1 * wv[kk].y;
    }
  }
  atomicAdd(&teacc[n2 * 2 + 0], a0x);
  atomicAdd(&teacc[n2 * 2 + 1], a0y);
  atomicAdd(&teacc[4608 + n2 * 2 + 0], a1x);
  atomicAdd(&teacc[4608 + n2 * 2 + 1], a1y);
}

// ---------------------------------------------------------------------------
// LayerNorm + adaLN modulate: out_bf16 = (teacc+bss2)[g] * LN(x) + (teacc+bss2)[b]
// ---------------------------------------------------------------------------
__global__ void k_ln_mod(const float* __restrict__ x, const float* __restrict__ lng,
                         const float* __restrict__ lnb, const float* __restrict__ teacc,
                         const float* __restrict__ bss2,
                         int gofs, int bofs, __hip_bfloat16* __restrict__ out) {
  int row = blockIdx.x;          // 0..4095
  int b = row >> 11;             // / 2048
  const float* xr = x + (size_t)row * 768;
  int tid = threadIdx.x;
  float v[3];
  float s = 0.f, sq = 0.f;
#pragma unroll
  for (int i = 0; i < 3; ++i) { v[i] = xr[tid + 256 * i]; s += v[i]; sq += v[i] * v[i]; }
#pragma unroll
  for (int o = 32; o > 0; o >>= 1) { s += __shfl_xor(s, o); sq += __shfl_xor(sq, o); }
  __shared__ float rs[4], rq[4];
  int w = tid >> 6, lane = tid & 63;
  if (lane == 0) { rs[w] = s; rq[w] = sq; }
  __syncthreads();
  s = rs[0] + rs[1] + rs[2] + rs[3];
  sq = rq[0] + rq[1] + rq[2] + rq[3];
  float mu = s * (1.f / 768.f);
  float var = sq * (1.f / 768.f) - mu * mu;
  float rstd = rsqrtf(var + 1e-5f);
  const float* tb = teacc + (size_t)b * 4608;
#pragma unroll
  for (int i = 0; i < 3; ++i) {
    int n = tid + 256 * i;
    float gv = tb[gofs + n] + bss2[gofs + n];
    float bv = tb[bofs + n] + bss2[bofs + n];
    float h = (v[i] - mu) * rstd * lng[n] + lnb[n];
    h = gv * h + bv;
    out[(size_t)row * 768 + n] = __float2bfloat16(h);
  }
}

// ---------------------------------------------------------------------------
// m97-style bf16 MFMA GEMM: C[M,N] = A[M,K] @ Bt[N,K]^T (both [row][k]).
// Tile BM x BN, BK=64, 4 waves (2x2), global_load_lds width=16 staging,
// XOR-swizzled LDS (phys_chunk = logical ^ (row&7)).
// Epilogues: 0=bias->f32, 1=bias+gelu(tanh)->bf16, 2=res+gate*(acc+bias)->f32
//            3=qkv fused: Q scaled ->qkvb, K ->qkvb, V -> VT transposed
// ---------------------------------------------------------------------------
template <int BM, int BN, int EPI>
__global__ __launch_bounds__(256)
void k_gemm(const __hip_bfloat16* __restrict__ A,
            const __hip_bfloat16* __restrict__ Bt,
            const float* __restrict__ bias,
            float* __restrict__ outF, __hip_bfloat16* __restrict__ outB,
            __hip_bfloat16* __restrict__ outV,
            const float* __restrict__ res, const float* __restrict__ teacc,
            const float* __restrict__ bss2,
            int gofs, int M, int N, int K) {
  constexpr int MI = BM / 32;
  constexpr int NI = BN / 32;
  __shared__ __align__(16) __hip_bfloat16 As[BM * 64];
  __shared__ __align__(16) __hip_bfloat16 Bs[BN * 64];
  const int tid = threadIdx.x;
  const int w = tid >> 6, lane = tid & 63;
  const int quad = lane >> 4, l16 = lane & 15;
  const int wm = w & 1, wn = w >> 1;
  const int m0 = blockIdx.y * BM, n0 = blockIdx.x * BN;
  const int srow = lane >> 3;
  const int sco = ((lane & 7) ^ srow) * 8;

  f32x4 acc[MI][NI] = {};

  for (int k0 = 0; k0 < K; k0 += 64) {
#pragma unroll
    for (int ii = 0; ii < BM / 32; ++ii) {
      int is = w * (BM / 32) + ii;
      const __hip_bfloat16* g = A + (size_t)(m0 + is * 8 + srow) * K + k0 + sco;
      __builtin_amdgcn_global_load_lds(
          (const __attribute__((address_space(1))) void*)g,
          (__attribute__((address_space(3))) void*)&As[is * 512], 16, 0, 0);
    }
#pragma unroll
    for (int ii = 0; ii < BN / 32; ++ii) {
      int is = w * (BN / 32) + ii;
      const __hip_bfloat16* g = Bt + (size_t)(n0 + is * 8 + srow) * K + k0 + sco;
      __builtin_amdgcn_global_load_lds(
          (const __attribute__((address_space(1))) void*)g,
          (__attribute__((address_space(3))) void*)&Bs[is * 512], 16, 0, 0);
    }
    __syncthreads();
#pragma unroll
    for (int ks = 0; ks < 2; ++ks) {
      bf16x8 af[MI], bfv[NI];
#pragma unroll
      for (int i = 0; i < MI; ++i) {
        int row = wm * (BM / 2) + i * 16 + l16;
        int cph = (ks * 4 + quad) ^ (row & 7);
        af[i] = *(const bf16x8*)&As[row * 64 + cph * 8];
      }
#pragma unroll
      for (int j = 0; j < NI; ++j) {
        int row = wn * (BN / 2) + j * 16 + l16;
        int cph = (ks * 4 + quad) ^ (row & 7);
        bfv[j] = *(const bf16x8*)&Bs[row * 64 + cph * 8];
      }
#pragma unroll
      for (int i = 0; i < MI; ++i)
#pragma unroll
        for (int j = 0; j < NI; ++j)
          acc[i][j] = __builtin_amdgcn_mfma_f32_16x16x32_bf16(af[i], bfv[j], acc[i][j], 0, 0, 0);
    }
    __syncthreads();
  }

#pragma unroll
  for (int j = 0; j < NI; ++j) {
    int col = n0 + wn * (BN / 2) + j * 16 + l16;
    float bs = bias[col];
#pragma unroll
    for (int i = 0; i < MI; ++i) {
      int row0 = m0 + wm * (BM / 2) + i * 16 + quad * 4;
      if (EPI == 3 && col >= 1536) {
        // V head: write transposed into VT[(b*12+nh)*64+dl][token], 8B packed
        int d = col - 1536;
        int nh = d >> 6, dl = d & 63;
        int bb = row0 >> 11, tok = row0 & 2047;
        __hip_bfloat16 tmp[4];
#pragma unroll
        for (int r = 0; r < 4; ++r) tmp[r] = __float2bfloat16(acc[i][j][r] + bs);
        *(uint2*)&outV[((size_t)(bb * 12 + nh) * 64 + dl) * 2048 + tok] = *(uint2*)tmp;
      } else {
#pragma unroll
        for (int r = 0; r < 4; ++r) {
          int row = row0 + r;
          float v = acc[i][j][r] + bs;
          size_t idx = (size_t)row * N + col;
          if (EPI == 0) {
            outF[idx] = v;
          } else if (EPI == 1) {
            // tanh-approx gelu: v - v/(e+1), e = exp2(2*log2e*0.79788456*(v+0.044715 v^3))
            float v2 = v * v;
            float u = v * (0.79788456080286536f + 0.035677408136300125f * v2);
            float e = fast_exp2(u * 2.8853900817779268f);
            float gl = v - v * __builtin_amdgcn_rcpf(e + 1.f);
            outB[idx] = __float2bfloat16(gl);
          } else if (EPI == 2) {
            float gate = teacc[(size_t)(row >> 11) * 4608 + gofs + col] + bss2[gofs + col];
            outF[idx] = res[idx] + gate * v;
          } else {  // EPI==3, Q/K heads
            float vq = (col < 768) ? v * SCALE_Q_LOG2E : v;
            outB[idx] = __float2bfloat16(vq);
          }
        }
      }
    }
  }
}

// ---------------------------------------------------------------------------
// MFMA flash attention — round-6 form (in-register softmax via swapped QK^T,
// 32x32x16 MFMA, cvt_pk+permlane32_swap, no P LDS round-trip; KV-split x2).
// Verified r6: k_attn dropped out of top-5, absmax unchanged.
// ---------------------------------------------------------------------------
__launch_bounds__(256)
__global__ void k_attn(const __hip_bfloat16* __restrict__ qkvb,
                       const __hip_bfloat16* __restrict__ VT,
                       float* __restrict__ Opart,   // [2][4096][768] f32
                       float* __restrict__ lpart) { // [2][4096][12]  f32
  __shared__ __align__(16) __hip_bfloat16 Ks[128 * 64];  // [tok][d], 8-chunk xor swizzle
  __shared__ __align__(16) __hip_bfloat16 Vs[64 * 128];  // [d][tok], 16-chunk xor swizzle

  const int tid = threadIdx.x;
  const int w = tid >> 6, lane = tid & 63;
  const int l32 = lane & 31, hi = lane >> 5;
  const int qt = blockIdx.x, nh = blockIdx.y;
  const int b = blockIdx.z >> 1, half = blockIdx.z & 1;
  const int bh = b * 12 + nh;

  const int qrow0 = b * 2048 + qt * 128 + w * 32;   // this warp's 32 q-rows
  // Q fragments (B-operand): lane holds Q[q=l32][d = dg*16 + hi*8 + j]
  bf16x8 qf[4];
#pragma unroll
  for (int dg = 0; dg < 4; ++dg)
    qf[dg] = *(const bf16x8*)(qkvb + (size_t)(qrow0 + l32) * 2304 + nh * 64 + dg * 16 + hi * 8);

  f32x16 o0 = {}, o1 = {};   // O accum: col d = dh*32 + l32, row q = (r&3)+8(r>>2)+4hi
  float lsum = 0.f;

  const int krow = lane >> 3;                       // K staging: 8 tok-rows/instr
  const int kco = ((lane & 7) ^ krow) * 8;          // pre-swizzled source chunk

  for (int kt = 0; kt < 8; ++kt) {
    const int tok0 = b * 2048 + half * 1024 + kt * 128;
    __syncthreads();   // prev tile's LDS reads retired
#pragma unroll
    for (int ii = 0; ii < 4; ++ii) {
      int i = w * 4 + ii;
      // K: tok-rows i*8 + (lane>>3), d-chunk swizzled by tok&7
      const __hip_bfloat16* gk =
          qkvb + (size_t)(tok0 + i * 8 + krow) * 2304 + 768 + nh * 64 + kco;
      __builtin_amdgcn_global_load_lds(
          (const __attribute__((address_space(1))) void*)gk,
          (__attribute__((address_space(3))) void*)&Ks[i * 512], 16, 0, 0);
      // V: d-rows i*4 + (lane>>4), tok-chunk swizzled by d&15
      int vd = i * 4 + (lane >> 4);
      const __hip_bfloat16* gv =
          VT + (size_t)(bh * 64 + vd) * 2048 + half * 1024 + kt * 128 +
          (((lane & 15) ^ (vd & 15)) * 8);
      __builtin_amdgcn_global_load_lds(
          (const __attribute__((address_space(1))) void*)gv,
          (__attribute__((address_space(3))) void*)&Vs[i * 512], 16, 0, 0);
    }
    __syncthreads();   // all K/V staged

#pragma unroll
    for (int g2 = 0; g2 < 4; ++g2) {   // 32-token groups within the 128-tile
      // ---- S^T = K Q^T : lane gets P-row slice for q = l32 ----
      f32x16 s = {};
      __builtin_amdgcn_s_setprio(1);
#pragma unroll
      for (int dg = 0; dg < 4; ++dg) {
        int tok = g2 * 32 + l32;
        int phys = (dg * 2 + hi) ^ (tok & 7);
        bf16x8 kf = *(const bf16x8*)&Ks[tok * 64 + phys * 8];
        s = __builtin_amdgcn_mfma_f32_32x32x16_bf16(kf, qf[dg], s, 0, 0, 0);
      }
      __builtin_amdgcn_s_setprio(0);

      // ---- P = exp2(S), row-sum, pack to PV A-frags in-register ----
      float p[16];
#pragma unroll
      for (int r = 0; r < 16; ++r) { p[r] = fast_exp2(s[r]); lsum += p[r]; }
      uint32_t wd[8];
#pragma unroll
      for (int i2 = 0; i2 < 8; ++i2)
        asm("v_cvt_pk_bf16_f32 %0, %1, %2" : "=v"(wd[i2]) : "v"(p[2 * i2]), "v"(p[2 * i2 + 1]));
      asm("v_permlane32_swap_b32 %0, %1" : "+v"(wd[0]), "+v"(wd[2]));
      asm("v_permlane32_swap_b32 %0, %1" : "+v"(wd[1]), "+v"(wd[3]));
      asm("v_permlane32_swap_b32 %0, %1" : "+v"(wd[4]), "+v"(wd[6]));
      asm("v_permlane32_swap_b32 %0, %1" : "+v"(wd[5]), "+v"(wd[7]));

      // ---- O += P V over the two 16-token slices of this group ----
      __builtin_amdgcn_s_setprio(1);
#pragma unroll
      for (int s01 = 0; s01 < 2; ++s01) {
        union { uint32_t u[4]; bf16x8 v; } fr;
        fr.u[0] = wd[s01 * 4 + 0]; fr.u[1] = wd[s01 * 4 + 1];
        fr.u[2] = wd[s01 * 4 + 2]; fr.u[3] = wd[s01 * 4 + 3];
        int ks = g2 * 2 + s01;
#pragma unroll
        for (int dh = 0; dh < 2; ++dh) {
          int row = dh * 32 + l32;
          int phys = (ks * 2 + hi) ^ (row & 15);
          bf16x8 vf = *(const bf16x8*)&Vs[row * 128 + phys * 8];
          if (dh == 0) o0 = __builtin_amdgcn_mfma_f32_32x32x16_bf16(fr.v, vf, o0, 0, 0, 0);
          else         o1 = __builtin_amdgcn_mfma_f32_32x32x16_bf16(fr.v, vf, o1, 0, 0, 0);
        }
      }
      __builtin_amdgcn_s_setprio(0);
    }
  }

  // ---- epilogue: partial O (f32, pre-division) + partial l ----
  lsum += __shfl_xor(lsum, 32);   // combine hi/lo token halves for q = l32
  {
    float* op = Opart + (size_t)half * 4096 * 768;
#pragma unroll
    for (int r = 0; r < 16; ++r) {
      int q = (r & 3) + 8 * (r >> 2) + 4 * hi;
      size_t rowofs = (size_t)(qrow0 + q) * 768 + nh * 64;
      op[rowofs + l32]      = o0[r];
      op[rowofs + 32 + l32] = o1[r];
    }
    if (lane < 32)
      lpart[((size_t)half * 4096 + qrow0 + l32) * 12 + nh] = lsum;
  }
}

// ---------------------------------------------------------------------------
// combine: out[row][nh*64+d] = (O0+O1)[row][nh*64+d] / (l0+l1)[row][nh]
// 4096 blocks x 192 threads; float4 reads, bf16x4 writes.
// ---------------------------------------------------------------------------
__global__ __launch_bounds__(192)
void k_attn_comb(const float* __restrict__ Opart, const float* __restrict__ lpart,
                 __hip_bfloat16* __restrict__ out) {
  int row = blockIdx.x;
  int tid = threadIdx.x;              // 0..191, handles cols [tid*4, tid*4+4)
  int c0 = tid * 4;
  int nh = c0 >> 6;
  float l = lpart[((size_t)row) * 12 + nh] + lpart[((size_t)4096 + row) * 12 + nh];
  float inv = 1.f / l;
  const float* o0 = Opart + (size_t)row * 768 + c0;
  const float* o1 = Opart + (size_t)(4096 + row) * 768 + c0;
  float4 a = *(const float4*)o0;
  float4 bq = *(const float4*)o1;
  __hip_bfloat16 t4[4];
  t4[0] = __float2bfloat16((a.x + bq.x) * inv);
  t4[1] = __float2bfloat16((a.y + bq.y) * inv);
  t4[2] = __float2bfloat16((a.z + bq.z) * inv);
  t4[3] = __float2bfloat16((a.w + bq.w) * inv);
  *(uint2*)&out[(size_t)row * 768 + c0] = *(uint2*)t4;
}

// ---------------------------------------------------------------------------
extern "C" void kernel_launch(void* const* d_in, const int* in_sizes, int n_in,
                              void* d_out, int out_size, void* d_ws, size_t ws_size,
                              hipStream_t stream) {
  const float* x      = (const float*)d_in[0];
  const float* t      = (const float*)d_in[1];
  const float* w_qkv  = (const float*)d_in[2];
  const float* b_qkv  = (const float*)d_in[3];
  const float* w_m1   = (const float*)d_in[4];
  const float* b_m1   = (const float*)d_in[5];
  const float* w_m2   = (const float*)d_in[6];
  const float* b_m2   = (const float*)d_in[7];
  const float* w_ss1  = (const float*)d_in[8];
  const float* b_ss1  = (const float*)d_in[9];
  const float* w_ss2  = (const float*)d_in[10];
  const float* b_ss2  = (const float*)d_in[11];
  const float* ln1_g  = (const float*)d_in[12];
  const float* ln1_b  = (const float*)d_in[13];
  const float* ln2_g  = (const float*)d_in[14];
  const float* ln2_b  = (const float*)d_in[15];
  const float* w_f1   = (const float*)d_in[16];
  const float* b_f1   = (const float*)d_in[17];
  const float* w_f2   = (const float*)d_in[18];
  const float* b_f2   = (const float*)d_in[19];
  float* out = (float*)d_out;

  char* ws = (char*)d_ws;
  size_t off = 0;
  auto alloc = [&](size_t bytes) -> char* {
    off = (off + 255) & ~(size_t)255;
    char* p = ws + off;
    off += bytes;
    return p;
  };
  __hip_bfloat16* wtq  = (__hip_bfloat16*)alloc((size_t)2304 * 768 * 2);
  __hip_bfloat16* wtm1 = (__hip_bfloat16*)alloc((size_t)3072 * 768 * 2);
  __hip_bfloat16* wtm2 = (__hip_bfloat16*)alloc((size_t)768 * 3072 * 2);
  __hip_bfloat16* wtf1 = (__hip_bfloat16*)alloc((size_t)3072 * 768 * 2);
  __hip_bfloat16* wtf2 = (__hip_bfloat16*)alloc((size_t)768 * 3072 * 2);
  float* tacc1 = (float*)alloc(9216 * 4);
  float* teacc = (float*)alloc(9216 * 4);
  __hip_bfloat16* h1   = (__hip_bfloat16*)alloc((size_t)4096 * 768 * 2);   // reused as h2
  __hip_bfloat16* qkvb = (__hip_bfloat16*)alloc((size_t)4096 * 2304 * 2);
  __hip_bfloat16* VT   = (__hip_bfloat16*)alloc((size_t)24 * 64 * 2048 * 2);
  __hip_bfloat16* attn = (__hip_bfloat16*)alloc((size_t)4096 * 768 * 2);
  __hip_bfloat16* act1 = (__hip_bfloat16*)alloc((size_t)4096 * 3072 * 2);  // reused as act2
  float* x1            = (float*)alloc((size_t)4096 * 768 * 4);
  float* Opart         = (float*)alloc((size_t)2 * 4096 * 768 * 4);
  float* lpart         = (float*)alloc((size_t)2 * 4096 * 12 * 4);

  (void)hipMemsetAsync(tacc1, 0, 9216 * 4, stream);
  (void)hipMemsetAsync(teacc, 0, 9216 * 4, stream);

  // prep: 5 weight transposes (64x64 tiles) + t-path stage 1 (16-k split)
  PrepArgs pa;
  pa.src[0] = w_qkv; pa.dst[0] = wtq;  pa.K[0] = 768;  pa.N[0] = 2304;
  pa.src[1] = w_m1;  pa.dst[1] = wtm1; pa.K[1] = 768;  pa.N[1] = 3072;
  pa.src[2] = w_m2;  pa.dst[2] = wtm2; pa.K[2] = 3072; pa.N[2] = 768;
  pa.src[3] = w_f1;  pa.dst[3] = wtf1; pa.K[3] = 768;  pa.N[3] = 3072;
  pa.src[4] = w_f2;  pa.dst[4] = wtf2; pa.K[4] = 3072; pa.N[4] = 768;
  pa.start[0] = 0;
  pa.start[1] = pa.start[0] + (2304 / 64) * (768 / 64);
  pa.start[2] = pa.start[1] + (3072 / 64) * (768 / 64);
  pa.start[3] = pa.start[2] + (768 / 64) * (3072 / 64);
  pa.start[4] = pa.start[3] + (3072 / 64) * (768 / 64);
  pa.start[5] = pa.start[4] + (768 / 64) * (3072 / 64);
  pa.tin = t; pa.w_ss1 = w_ss1; pa.tacc1 = tacc1;
  int tvec1_blocks = 18 * 48;  // (4608/256) x (768/16)
  k_prep<<<pa.start[5] + tvec1_blocks, 256, 0, stream>>>(pa);

  // t-path stage 2 (silu+bias inline, staged float2 loads)
  k_tvec2_silu<<<dim3(4608 / 512, 4608 / 64), 256, 0, stream>>>(tacc1, b_ss1, w_ss2, teacc);

  // block 1: LN1+mod -> qkv GEMM (Q scaled, V transposed to VT) -> attn -> mFFN
  k_ln_mod<<<4096, 256, 0, stream>>>(x, ln1_g, ln1_b, teacc, b_ss2, 0, 768, h1);
  k_gemm<64, 128, 3><<<dim3(2304 / 128, 4096 / 64), 256, 0, stream>>>(
      h1, wtq, b_qkv, nullptr, qkvb, VT, nullptr, nullptr, nullptr, 0, 4096, 2304, 768);
  k_attn<<<dim3(16, 12, 4), 256, 0, stream>>>(qkvb, VT, Opart, lpart);
  k_attn_comb<<<4096, 192, 0, stream>>>(Opart, lpart, attn);
  k_gemm<128, 128, 1><<<dim3(3072 / 128, 4096 / 128), 256, 0, stream>>>(
      attn, wtm1, b_m1, nullptr, act1, nullptr, nullptr, nullptr, nullptr, 0, 4096, 3072, 768);
  k_gemm<64, 64, 2><<<dim3(768 / 64, 4096 / 64), 256, 0, stream>>>(
      act1, wtm2, b_m2, x1, nullptr, nullptr, x, teacc, b_ss2, 1536, 4096, 768, 3072);

  // block 2: LN2+mod -> FFN
  k_ln_mod<<<4096, 256, 0, stream>>>(x1, ln2_g, ln2_b, teacc, b_ss2, 2304, 3072, h1);
  k_gemm<128, 128, 1><<<dim3(3072 / 128, 4096 / 128), 256, 0, stream>>>(
      h1, wtf1, b_f1, nullptr, act1, nullptr, nullptr, nullptr, nullptr, 0, 4096, 3072, 768);
  k_gemm<64, 64, 2><<<dim3(768 / 64, 4096 / 64), 256, 0, stream>>>(
      act1, wtf2, b_f2, out, nullptr, nullptr, x1, teacc, b_ss2, 3840, 4096, 768, 3072);
}

// Round 8
// 418.758 us; speedup vs baseline: 1.2733x; 1.0201x over previous
//
#include <hip/hip_runtime.h>
#include <hip/hip_bf16.h>
#include <cstdint>

typedef __bf16 bf16x8 __attribute__((ext_vector_type(8)));
typedef float f32x4 __attribute__((ext_vector_type(4)));
typedef float f32x16 __attribute__((ext_vector_type(16)));

// Q pre-scale: (1/sqrt(768)) * log2(e)  -> attention exp becomes raw exp2
#define SCALE_Q_LOG2E 0.052058770734702875f

// fast exp2 via v_exp_f32 (NOTE: __exp2f collides with glibc math.h macro)
__device__ inline float fast_exp2(float x) { return __builtin_amdgcn_exp2f(x); }

// ---------------------------------------------------------------------------
// prep kernel: 5 weight transposes (fp32->bf16, dst[n][k]=src[k][n]) PLUS
// t-path stage 1 ([2,768]@[768,4608] k-split atomic) in one dispatch.
// ---------------------------------------------------------------------------
struct PrepArgs {
  const float* src[5];
  __hip_bfloat16* dst[5];
  int K[5], N[5];
  int start[6];           // transpose block ranges; start[5] = total transpose blocks
  const float* tin;       // t input [2,768]
  const float* w_ss1;     // [768,4608]
  float* tacc1;           // [2,4608] (zeroed)
};

__global__ __launch_bounds__(256) void k_prep(PrepArgs pa) {
  __shared__ float tile[64][65];
  int bid = blockIdx.x;
  int tid = threadIdx.x;
  if (bid < pa.start[5]) {
    int i = 0;
#pragma unroll
    for (int j = 1; j < 5; ++j)
      if (bid >= pa.start[j]) i = j;
    int t0 = bid - pa.start[i];
    int N = pa.N[i], K = pa.K[i];
    int ntx = N >> 6;
    int bx = t0 % ntx, by = t0 / ntx;
    const float* src = pa.src[i];
    __hip_bfloat16* dst = pa.dst[i];
    int n0 = bx * 64, k0 = by * 64;
    int c4 = tid & 15, rr = tid >> 4;   // 16 float4-cols x 16 rows per pass
    float4 v[4];
#pragma unroll
    for (int p = 0; p < 4; ++p)
      v[p] = *(const float4*)&src[(size_t)(k0 + rr + 16 * p) * N + n0 + c4 * 4];
#pragma unroll
    for (int p = 0; p < 4; ++p) {
      tile[rr + 16 * p][c4 * 4 + 0] = v[p].x;
      tile[rr + 16 * p][c4 * 4 + 1] = v[p].y;
      tile[rr + 16 * p][c4 * 4 + 2] = v[p].z;
      tile[rr + 16 * p][c4 * 4 + 3] = v[p].w;
    }
    __syncthreads();
    int kg = tid & 15, nl = tid >> 4;
#pragma unroll
    for (int p = 0; p < 4; ++p) {
      int n = nl + 16 * p;
      __hip_bfloat16 t4[4];
#pragma unroll
      for (int j = 0; j < 4; ++j) t4[j] = __float2bfloat16(tile[kg * 4 + j][n]);
      *(uint2*)&dst[(size_t)(n0 + n) * K + k0 + kg * 4] = *(uint2*)t4;
    }
  } else {
    // t-path stage 1: 18 n-blocks x 48 k-blocks (16 k each), staged loads.
    int t0 = bid - pa.start[5];
    int nb = t0 % 18, kb0 = (t0 / 18) * 16;
    int n = nb * 256 + tid;
    float wv[16];
#pragma unroll
    for (int kk = 0; kk < 16; ++kk)
      wv[kk] = pa.w_ss1[(size_t)(kb0 + kk) * 4608 + n];
    float a0 = 0.f, a1 = 0.f;
#pragma unroll
    for (int kk = 0; kk < 16; ++kk) {
      a0 += pa.tin[kb0 + kk] * wv[kk];
      a1 += pa.tin[768 + kb0 + kk] * wv[kk];
    }
    atomicAdd(&pa.tacc1[n], a0);
    atomicAdd(&pa.tacc1[4608 + n], a1);
  }
}

// ---------------------------------------------------------------------------
// t-path stage 2 with inline silu+bias on the input (staged float2 loads).
// ---------------------------------------------------------------------------
__global__ void k_tvec2_silu(const float* __restrict__ tacc1, const float* __restrict__ bss1,
                             const float* __restrict__ W, float* __restrict__ teacc) {
  int n2 = blockIdx.x * 256 + threadIdx.x;   // float2 column index, 0..2303
  int kb = blockIdx.y * 64;
  float a0x = 0.f, a0y = 0.f, a1x = 0.f, a1y = 0.f;
#pragma unroll 1
  for (int kc = 0; kc < 4; ++kc) {
    int k0 = kb + kc * 16;
    float2 wv[16];
#pragma unroll
    for (int kk = 0; kk < 16; ++kk)
      wv[kk] = *(const float2*)&W[(size_t)(k0 + kk) * 4608 + n2 * 2];
#pragma unroll
    for (int kk = 0; kk < 16; ++kk) {
      int k = k0 + kk;
      float bs = bss1[k];
      float t0 = tacc1[k] + bs;
      float t1 = tacc1[4608 + k] + bs;
      t0 = t0 / (1.f + expf(-t0));
      t1 = t1 / (1.f + expf(-t1));
      a0x += t0 * wv[kk].x; a0y += t0 * wv[kk].y;
      a1x += t1 * wv[kk].x; a1y += t1 * wv[kk].y;
    }
  }
  atomicAdd(&teacc[n2 * 2 + 0], a0x);
  atomicAdd(&teacc[n2 * 2 + 1], a0y);
  atomicAdd(&teacc[4608 + n2 * 2 + 0], a1x);
  atomicAdd(&teacc[4608 + n2 * 2 + 1], a1y);
}

// ---------------------------------------------------------------------------
// LayerNorm + adaLN modulate: out_bf16 = (teacc+bss2)[g] * LN(x) + (teacc+bss2)[b]
// ---------------------------------------------------------------------------
__global__ void k_ln_mod(const float* __restrict__ x, const float* __restrict__ lng,
                         const float* __restrict__ lnb, const float* __restrict__ teacc,
                         const float* __restrict__ bss2,
                         int gofs, int bofs, __hip_bfloat16* __restrict__ out) {
  int row = blockIdx.x;          // 0..4095
  int b = row >> 11;             // / 2048
  const float* xr = x + (size_t)row * 768;
  int tid = threadIdx.x;
  float v[3];
  float s = 0.f, sq = 0.f;
#pragma unroll
  for (int i = 0; i < 3; ++i) { v[i] = xr[tid + 256 * i]; s += v[i]; sq += v[i] * v[i]; }
#pragma unroll
  for (int o = 32; o > 0; o >>= 1) { s += __shfl_xor(s, o); sq += __shfl_xor(sq, o); }
  __shared__ float rs[4], rq[4];
  int w = tid >> 6, lane = tid & 63;
  if (lane == 0) { rs[w] = s; rq[w] = sq; }
  __syncthreads();
  s = rs[0] + rs[1] + rs[2] + rs[3];
  sq = rq[0] + rq[1] + rq[2] + rq[3];
  float mu = s * (1.f / 768.f);
  float var = sq * (1.f / 768.f) - mu * mu;
  float rstd = rsqrtf(var + 1e-5f);
  const float* tb = teacc + (size_t)b * 4608;
#pragma unroll
  for (int i = 0; i < 3; ++i) {
    int n = tid + 256 * i;
    float gv = tb[gofs + n] + bss2[gofs + n];
    float bv = tb[bofs + n] + bss2[bofs + n];
    float h = (v[i] - mu) * rstd * lng[n] + lnb[n];
    h = gv * h + bv;
    out[(size_t)row * 768 + n] = __float2bfloat16(h);
  }
}

// ---------------------------------------------------------------------------
// m97-style bf16 MFMA GEMM: C[M,N] = A[M,K] @ Bt[N,K]^T (both [row][k]).
// Tile BM x BN, BK=64, 4 waves (2x2), global_load_lds width=16 staging,
// XOR-swizzled LDS (phys_chunk = logical ^ (row&7)).
// r8: + bijective XCD swizzle (T1) — all grids are %8==0.
// Epilogues: 0=bias->f32, 1=bias+gelu(tanh)->bf16,
//            3=qkv fused: Q scaled ->qkvb, K ->qkvb, V -> VT transposed
// ---------------------------------------------------------------------------
template <int BM, int BN, int EPI>
__global__ __launch_bounds__(256)
void k_gemm(const __hip_bfloat16* __restrict__ A,
            const __hip_bfloat16* __restrict__ Bt,
            const float* __restrict__ bias,
            float* __restrict__ outF, __hip_bfloat16* __restrict__ outB,
            __hip_bfloat16* __restrict__ outV,
            const float* __restrict__ res, const float* __restrict__ teacc,
            const float* __restrict__ bss2,
            int gofs, int M, int N, int K) {
  constexpr int MI = BM / 32;
  constexpr int NI = BN / 32;
  __shared__ __align__(16) __hip_bfloat16 As[BM * 64];
  __shared__ __align__(16) __hip_bfloat16 Bs[BN * 64];
  const int tid = threadIdx.x;
  const int w = tid >> 6, lane = tid & 63;
  const int quad = lane >> 4, l16 = lane & 15;
  const int wm = w & 1, wn = w >> 1;
  // XCD-aware bijective block swizzle (grid count % 8 == 0 at all call sites)
  const int nx = gridDim.x;
  const int lin = blockIdx.y * nx + blockIdx.x;
  const int cpx = (nx * gridDim.y) >> 3;
  const int sw = (lin & 7) * cpx + (lin >> 3);
  const int m0 = (sw / nx) * BM, n0 = (sw % nx) * BN;
  const int srow = lane >> 3;
  const int sco = ((lane & 7) ^ srow) * 8;

  f32x4 acc[MI][NI] = {};

  for (int k0 = 0; k0 < K; k0 += 64) {
#pragma unroll
    for (int ii = 0; ii < BM / 32; ++ii) {
      int is = w * (BM / 32) + ii;
      const __hip_bfloat16* g = A + (size_t)(m0 + is * 8 + srow) * K + k0 + sco;
      __builtin_amdgcn_global_load_lds(
          (const __attribute__((address_space(1))) void*)g,
          (__attribute__((address_space(3))) void*)&As[is * 512], 16, 0, 0);
    }
#pragma unroll
    for (int ii = 0; ii < BN / 32; ++ii) {
      int is = w * (BN / 32) + ii;
      const __hip_bfloat16* g = Bt + (size_t)(n0 + is * 8 + srow) * K + k0 + sco;
      __builtin_amdgcn_global_load_lds(
          (const __attribute__((address_space(1))) void*)g,
          (__attribute__((address_space(3))) void*)&Bs[is * 512], 16, 0, 0);
    }
    __syncthreads();
#pragma unroll
    for (int ks = 0; ks < 2; ++ks) {
      bf16x8 af[MI], bfv[NI];
#pragma unroll
      for (int i = 0; i < MI; ++i) {
        int row = wm * (BM / 2) + i * 16 + l16;
        int cph = (ks * 4 + quad) ^ (row & 7);
        af[i] = *(const bf16x8*)&As[row * 64 + cph * 8];
      }
#pragma unroll
      for (int j = 0; j < NI; ++j) {
        int row = wn * (BN / 2) + j * 16 + l16;
        int cph = (ks * 4 + quad) ^ (row & 7);
        bfv[j] = *(const bf16x8*)&Bs[row * 64 + cph * 8];
      }
#pragma unroll
      for (int i = 0; i < MI; ++i)
#pragma unroll
        for (int j = 0; j < NI; ++j)
          acc[i][j] = __builtin_amdgcn_mfma_f32_16x16x32_bf16(af[i], bfv[j], acc[i][j], 0, 0, 0);
    }
    __syncthreads();
  }

#pragma unroll
  for (int j = 0; j < NI; ++j) {
    int col = n0 + wn * (BN / 2) + j * 16 + l16;
    float bs = bias[col];
#pragma unroll
    for (int i = 0; i < MI; ++i) {
      int row0 = m0 + wm * (BM / 2) + i * 16 + quad * 4;
      if (EPI == 3 && col >= 1536) {
        // V head: write transposed into VT[(b*12+nh)*64+dl][token], 8B packed
        int d = col - 1536;
        int nh = d >> 6, dl = d & 63;
        int bb = row0 >> 11, tok = row0 & 2047;
        __hip_bfloat16 tmp[4];
#pragma unroll
        for (int r = 0; r < 4; ++r) tmp[r] = __float2bfloat16(acc[i][j][r] + bs);
        *(uint2*)&outV[((size_t)(bb * 12 + nh) * 64 + dl) * 2048 + tok] = *(uint2*)tmp;
      } else {
#pragma unroll
        for (int r = 0; r < 4; ++r) {
          int row = row0 + r;
          float v = acc[i][j][r] + bs;
          size_t idx = (size_t)row * N + col;
          if (EPI == 0) {
            outF[idx] = v;
          } else if (EPI == 1) {
            // tanh-approx gelu: v - v/(e+1), e = exp2(2*log2e*0.79788456*(v+0.044715 v^3))
            float v2 = v * v;
            float u = v * (0.79788456080286536f + 0.035677408136300125f * v2);
            float e = fast_exp2(u * 2.8853900817779268f);
            float gl = v - v * __builtin_amdgcn_rcpf(e + 1.f);
            outB[idx] = __float2bfloat16(gl);
          } else {  // EPI==3, Q/K heads
            float vq = (col < 768) ? v * SCALE_Q_LOG2E : v;
            outB[idx] = __float2bfloat16(vq);
          }
        }
      }
    }
  }
}

// ---------------------------------------------------------------------------
// r8: dedicated EPI2 GEMM (second FFN, N=768 K=3072): BM=BN=64, BK=128.
// Same 32KB LDS (so occupancy unchanged — avoids the m132 BK trap) but
// K-steps halve 48->24 and MFMA-per-barrier doubles 8->16 (the EPI2 64x64
// BK=64 tile had the worst MFMA:barrier density in the pipeline).
// 16-chunk XOR swizzle ^(row&15) — same pattern as attn's Vs (proven).
// Epilogue: out = res + gate*(acc + bias). + XCD swizzle.
// ---------------------------------------------------------------------------
__global__ __launch_bounds__(256)
void k_gemm2(const __hip_bfloat16* __restrict__ A,
             const __hip_bfloat16* __restrict__ Bt,
             const float* __restrict__ bias,
             float* __restrict__ outF,
             const float* __restrict__ res, const float* __restrict__ teacc,
             const float* __restrict__ bss2,
             int gofs, int M, int N, int K) {
  __shared__ __align__(16) __hip_bfloat16 As[64 * 128];
  __shared__ __align__(16) __hip_bfloat16 Bs[64 * 128];
  const int tid = threadIdx.x;
  const int w = tid >> 6, lane = tid & 63;
  const int quad = lane >> 4, l16 = lane & 15;
  const int wm = w & 1, wn = w >> 1;
  const int nx = gridDim.x;
  const int lin = blockIdx.y * nx + blockIdx.x;
  const int cpx = (nx * gridDim.y) >> 3;
  const int sw = (lin & 7) * cpx + (lin >> 3);
  const int m0 = (sw / nx) * 64, n0 = (sw % nx) * 64;
  const int srow4 = lane >> 4;                    // 4 rows per 1KB instr

  f32x4 acc[2][2] = {};

  for (int k0 = 0; k0 < K; k0 += 128) {
#pragma unroll
    for (int ii = 0; ii < 4; ++ii) {
      int i = w * 4 + ii;                         // 16 instrs cover 64 rows
      int row = i * 4 + srow4;
      int sc = ((lane & 15) ^ (row & 15)) * 8;
      const __hip_bfloat16* gA = A + (size_t)(m0 + row) * K + k0 + sc;
      __builtin_amdgcn_global_load_lds(
          (const __attribute__((address_space(1))) void*)gA,
          (__attribute__((address_space(3))) void*)&As[i * 512], 16, 0, 0);
      const __hip_bfloat16* gB = Bt + (size_t)(n0 + row) * K + k0 + sc;
      __builtin_amdgcn_global_load_lds(
          (const __attribute__((address_space(1))) void*)gB,
          (__attribute__((address_space(3))) void*)&Bs[i * 512], 16, 0, 0);
    }
    __syncthreads();
#pragma unroll
    for (int ks = 0; ks < 4; ++ks) {
      bf16x8 af[2], bfv[2];
#pragma unroll
      for (int i = 0; i < 2; ++i) {
        int row = wm * 32 + i * 16 + l16;
        int phys = (ks * 4 + quad) ^ (row & 15);
        af[i] = *(const bf16x8*)&As[row * 128 + phys * 8];
      }
#pragma unroll
      for (int j = 0; j < 2; ++j) {
        int row = wn * 32 + j * 16 + l16;
        int phys = (ks * 4 + quad) ^ (row & 15);
        bfv[j] = *(const bf16x8*)&Bs[row * 128 + phys * 8];
      }
#pragma unroll
      for (int i = 0; i < 2; ++i)
#pragma unroll
        for (int j = 0; j < 2; ++j)
          acc[i][j] = __builtin_amdgcn_mfma_f32_16x16x32_bf16(af[i], bfv[j], acc[i][j], 0, 0, 0);
    }
    __syncthreads();
  }

#pragma unroll
  for (int j = 0; j < 2; ++j) {
    int col = n0 + wn * 32 + j * 16 + l16;
    float bs = bias[col];
#pragma unroll
    for (int i = 0; i < 2; ++i) {
      int row0 = m0 + wm * 32 + i * 16 + quad * 4;
#pragma unroll
      for (int r = 0; r < 4; ++r) {
        int row = row0 + r;
        float v = acc[i][j][r] + bs;
        size_t idx = (size_t)row * N + col;
        float gate = teacc[(size_t)(row >> 11) * 4608 + gofs + col] + bss2[gofs + col];
        outF[idx] = res[idx] + gate * v;
      }
    }
  }
}

// ---------------------------------------------------------------------------
// MFMA flash attention — round-6 form (in-register softmax via swapped QK^T,
// 32x32x16 MFMA, cvt_pk+permlane32_swap, no P LDS round-trip; KV-split x2).
// r8: Opart now bf16 (halves partial-O traffic; downstream is bf16 anyway).
// ---------------------------------------------------------------------------
__launch_bounds__(256)
__global__ void k_attn(const __hip_bfloat16* __restrict__ qkvb,
                       const __hip_bfloat16* __restrict__ VT,
                       __hip_bfloat16* __restrict__ Opart,  // [2][4096][768] bf16
                       float* __restrict__ lpart) {         // [2][4096][12]  f32
  __shared__ __align__(16) __hip_bfloat16 Ks[128 * 64];  // [tok][d], 8-chunk xor swizzle
  __shared__ __align__(16) __hip_bfloat16 Vs[64 * 128];  // [d][tok], 16-chunk xor swizzle

  const int tid = threadIdx.x;
  const int w = tid >> 6, lane = tid & 63;
  const int l32 = lane & 31, hi = lane >> 5;
  const int qt = blockIdx.x, nh = blockIdx.y;
  const int b = blockIdx.z >> 1, half = blockIdx.z & 1;
  const int bh = b * 12 + nh;

  const int qrow0 = b * 2048 + qt * 128 + w * 32;   // this warp's 32 q-rows
  // Q fragments (B-operand): lane holds Q[q=l32][d = dg*16 + hi*8 + j]
  bf16x8 qf[4];
#pragma unroll
  for (int dg = 0; dg < 4; ++dg)
    qf[dg] = *(const bf16x8*)(qkvb + (size_t)(qrow0 + l32) * 2304 + nh * 64 + dg * 16 + hi * 8);

  f32x16 o0 = {}, o1 = {};   // O accum: col d = dh*32 + l32, row q = (r&3)+8(r>>2)+4hi
  float lsum = 0.f;

  const int krow = lane >> 3;                       // K staging: 8 tok-rows/instr
  const int kco = ((lane & 7) ^ krow) * 8;          // pre-swizzled source chunk

  for (int kt = 0; kt < 8; ++kt) {
    const int tok0 = b * 2048 + half * 1024 + kt * 128;
    __syncthreads();   // prev tile's LDS reads retired
#pragma unroll
    for (int ii = 0; ii < 4; ++ii) {
      int i = w * 4 + ii;
      // K: tok-rows i*8 + (lane>>3), d-chunk swizzled by tok&7
      const __hip_bfloat16* gk =
          qkvb + (size_t)(tok0 + i * 8 + krow) * 2304 + 768 + nh * 64 + kco;
      __builtin_amdgcn_global_load_lds(
          (const __attribute__((address_space(1))) void*)gk,
          (__attribute__((address_space(3))) void*)&Ks[i * 512], 16, 0, 0);
      // V: d-rows i*4 + (lane>>4), tok-chunk swizzled by d&15
      int vd = i * 4 + (lane >> 4);
      const __hip_bfloat16* gv =
          VT + (size_t)(bh * 64 + vd) * 2048 + half * 1024 + kt * 128 +
          (((lane & 15) ^ (vd & 15)) * 8);
      __builtin_amdgcn_global_load_lds(
          (const __attribute__((address_space(1))) void*)gv,
          (__attribute__((address_space(3))) void*)&Vs[i * 512], 16, 0, 0);
    }
    __syncthreads();   // all K/V staged

#pragma unroll
    for (int g2 = 0; g2 < 4; ++g2) {   // 32-token groups within the 128-tile
      // ---- S^T = K Q^T : lane gets P-row slice for q = l32 ----
      f32x16 s = {};
      __builtin_amdgcn_s_setprio(1);
#pragma unroll
      for (int dg = 0; dg < 4; ++dg) {
        int tok = g2 * 32 + l32;
        int phys = (dg * 2 + hi) ^ (tok & 7);
        bf16x8 kf = *(const bf16x8*)&Ks[tok * 64 + phys * 8];
        s = __builtin_amdgcn_mfma_f32_32x32x16_bf16(kf, qf[dg], s, 0, 0, 0);
      }
      __builtin_amdgcn_s_setprio(0);

      // ---- P = exp2(S), row-sum, pack to PV A-frags in-register ----
      float p[16];
#pragma unroll
      for (int r = 0; r < 16; ++r) { p[r] = fast_exp2(s[r]); lsum += p[r]; }
      uint32_t wd[8];
#pragma unroll
      for (int i2 = 0; i2 < 8; ++i2)
        asm("v_cvt_pk_bf16_f32 %0, %1, %2" : "=v"(wd[i2]) : "v"(p[2 * i2]), "v"(p[2 * i2 + 1]));
      asm("v_permlane32_swap_b32 %0, %1" : "+v"(wd[0]), "+v"(wd[2]));
      asm("v_permlane32_swap_b32 %0, %1" : "+v"(wd[1]), "+v"(wd[3]));
      asm("v_permlane32_swap_b32 %0, %1" : "+v"(wd[4]), "+v"(wd[6]));
      asm("v_permlane32_swap_b32 %0, %1" : "+v"(wd[5]), "+v"(wd[7]));

      // ---- O += P V over the two 16-token slices of this group ----
      __builtin_amdgcn_s_setprio(1);
#pragma unroll
      for (int s01 = 0; s01 < 2; ++s01) {
        union { uint32_t u[4]; bf16x8 v; } fr;
        fr.u[0] = wd[s01 * 4 + 0]; fr.u[1] = wd[s01 * 4 + 1];
        fr.u[2] = wd[s01 * 4 + 2]; fr.u[3] = wd[s01 * 4 + 3];
        int ks = g2 * 2 + s01;
#pragma unroll
        for (int dh = 0; dh < 2; ++dh) {
          int row = dh * 32 + l32;
          int phys = (ks * 2 + hi) ^ (row & 15);
          bf16x8 vf = *(const bf16x8*)&Vs[row * 128 + phys * 8];
          if (dh == 0) o0 = __builtin_amdgcn_mfma_f32_32x32x16_bf16(fr.v, vf, o0, 0, 0, 0);
          else         o1 = __builtin_amdgcn_mfma_f32_32x32x16_bf16(fr.v, vf, o1, 0, 0, 0);
        }
      }
      __builtin_amdgcn_s_setprio(0);
    }
  }

  // ---- epilogue: partial O (bf16, pre-division) + partial l ----
  lsum += __shfl_xor(lsum, 32);   // combine hi/lo token halves for q = l32
  {
    __hip_bfloat16* op = Opart + (size_t)half * 4096 * 768;
#pragma unroll
    for (int r = 0; r < 16; ++r) {
      int q = (r & 3) + 8 * (r >> 2) + 4 * hi;
      size_t rowofs = (size_t)(qrow0 + q) * 768 + nh * 64;
      op[rowofs + l32]      = __float2bfloat16(o0[r]);
      op[rowofs + 32 + l32] = __float2bfloat16(o1[r]);
    }
    if (lane < 32)
      lpart[((size_t)half * 4096 + qrow0 + l32) * 12 + nh] = lsum;
  }
}

// ---------------------------------------------------------------------------
// combine: out[row][nh*64+d] = (O0+O1)[row][nh*64+d] / (l0+l1)[row][nh]
// 4096 blocks x 192 threads; uint2 bf16 reads, bf16x4 writes.
// ---------------------------------------------------------------------------
__global__ __launch_bounds__(192)
void k_attn_comb(const __hip_bfloat16* __restrict__ Opart, const float* __restrict__ lpart,
                 __hip_bfloat16* __restrict__ out) {
  int row = blockIdx.x;
  int tid = threadIdx.x;              // 0..191, handles cols [tid*4, tid*4+4)
  int c0 = tid * 4;
  int nh = c0 >> 6;
  float l = lpart[((size_t)row) * 12 + nh] + lpart[((size_t)4096 + row) * 12 + nh];
  float inv = 1.f / l;
  uint2 u0 = *(const uint2*)&Opart[(size_t)row * 768 + c0];
  uint2 u1 = *(const uint2*)&Opart[(size_t)(4096 + row) * 768 + c0];
  const __hip_bfloat16* p0 = (const __hip_bfloat16*)&u0;
  const __hip_bfloat16* p1 = (const __hip_bfloat16*)&u1;
  __hip_bfloat16 t4[4];
#pragma unroll
  for (int j = 0; j < 4; ++j)
    t4[j] = __float2bfloat16((__bfloat162float(p0[j]) + __bfloat162float(p1[j])) * inv);
  *(uint2*)&out[(size_t)row * 768 + c0] = *(uint2*)t4;
}

// ---------------------------------------------------------------------------
extern "C" void kernel_launch(void* const* d_in, const int* in_sizes, int n_in,
                              void* d_out, int out_size, void* d_ws, size_t ws_size,
                              hipStream_t stream) {
  const float* x      = (const float*)d_in[0];
  const float* t      = (const float*)d_in[1];
  const float* w_qkv  = (const float*)d_in[2];
  const float* b_qkv  = (const float*)d_in[3];
  const float* w_m1   = (const float*)d_in[4];
  const float* b_m1   = (const float*)d_in[5];
  const float* w_m2   = (const float*)d_in[6];
  const float* b_m2   = (const float*)d_in[7];
  const float* w_ss1  = (const float*)d_in[8];
  const float* b_ss1  = (const float*)d_in[9];
  const float* w_ss2  = (const float*)d_in[10];
  const float* b_ss2  = (const float*)d_in[11];
  const float* ln1_g  = (const float*)d_in[12];
  const float* ln1_b  = (const float*)d_in[13];
  const float* ln2_g  = (const float*)d_in[14];
  const float* ln2_b  = (const float*)d_in[15];
  const float* w_f1   = (const float*)d_in[16];
  const float* b_f1   = (const float*)d_in[17];
  const float* w_f2   = (const float*)d_in[18];
  const float* b_f2   = (const float*)d_in[19];
  float* out = (float*)d_out;

  char* ws = (char*)d_ws;
  size_t off = 0;
  auto alloc = [&](size_t bytes) -> char* {
    off = (off + 255) & ~(size_t)255;
    char* p = ws + off;
    off += bytes;
    return p;
  };
  __hip_bfloat16* wtq  = (__hip_bfloat16*)alloc((size_t)2304 * 768 * 2);
  __hip_bfloat16* wtm1 = (__hip_bfloat16*)alloc((size_t)3072 * 768 * 2);
  __hip_bfloat16* wtm2 = (__hip_bfloat16*)alloc((size_t)768 * 3072 * 2);
  __hip_bfloat16* wtf1 = (__hip_bfloat16*)alloc((size_t)3072 * 768 * 2);
  __hip_bfloat16* wtf2 = (__hip_bfloat16*)alloc((size_t)768 * 3072 * 2);
  float* tacc1 = (float*)alloc(9216 * 4);
  float* teacc = (float*)alloc(9216 * 4);
  __hip_bfloat16* h1   = (__hip_bfloat16*)alloc((size_t)4096 * 768 * 2);   // reused as h2
  __hip_bfloat16* qkvb = (__hip_bfloat16*)alloc((size_t)4096 * 2304 * 2);
  __hip_bfloat16* VT   = (__hip_bfloat16*)alloc((size_t)24 * 64 * 2048 * 2);
  __hip_bfloat16* attn = (__hip_bfloat16*)alloc((size_t)4096 * 768 * 2);
  __hip_bfloat16* act1 = (__hip_bfloat16*)alloc((size_t)4096 * 3072 * 2);  // reused as act2
  float* x1            = (float*)alloc((size_t)4096 * 768 * 4);
  __hip_bfloat16* Opart = (__hip_bfloat16*)alloc((size_t)2 * 4096 * 768 * 2);
  float* lpart         = (float*)alloc((size_t)2 * 4096 * 12 * 4);

  (void)hipMemsetAsync(tacc1, 0, 9216 * 4, stream);
  (void)hipMemsetAsync(teacc, 0, 9216 * 4, stream);

  // prep: 5 weight transposes (64x64 tiles) + t-path stage 1 (16-k split)
  PrepArgs pa;
  pa.src[0] = w_qkv; pa.dst[0] = wtq;  pa.K[0] = 768;  pa.N[0] = 2304;
  pa.src[1] = w_m1;  pa.dst[1] = wtm1; pa.K[1] = 768;  pa.N[1] = 3072;
  pa.src[2] = w_m2;  pa.dst[2] = wtm2; pa.K[2] = 3072; pa.N[2] = 768;
  pa.src[3] = w_f1;  pa.dst[3] = wtf1; pa.K[3] = 768;  pa.N[3] = 3072;
  pa.src[4] = w_f2;  pa.dst[4] = wtf2; pa.K[4] = 3072; pa.N[4] = 768;
  pa.start[0] = 0;
  pa.start[1] = pa.start[0] + (2304 / 64) * (768 / 64);
  pa.start[2] = pa.start[1] + (3072 / 64) * (768 / 64);
  pa.start[3] = pa.start[2] + (768 / 64) * (3072 / 64);
  pa.start[4] = pa.start[3] + (3072 / 64) * (768 / 64);
  pa.start[5] = pa.start[4] + (768 / 64) * (3072 / 64);
  pa.tin = t; pa.w_ss1 = w_ss1; pa.tacc1 = tacc1;
  int tvec1_blocks = 18 * 48;  // (4608/256) x (768/16)
  k_prep<<<pa.start[5] + tvec1_blocks, 256, 0, stream>>>(pa);

  // t-path stage 2 (silu+bias inline, staged float2 loads)
  k_tvec2_silu<<<dim3(4608 / 512, 4608 / 64), 256, 0, stream>>>(tacc1, b_ss1, w_ss2, teacc);

  // block 1: LN1+mod -> qkv GEMM (Q scaled, V transposed to VT) -> attn -> mFFN
  k_ln_mod<<<4096, 256, 0, stream>>>(x, ln1_g, ln1_b, teacc, b_ss2, 0, 768, h1);
  k_gemm<64, 128, 3><<<dim3(2304 / 128, 4096 / 64), 256, 0, stream>>>(
      h1, wtq, b_qkv, nullptr, qkvb, VT, nullptr, nullptr, nullptr, 0, 4096, 2304, 768);
  k_attn<<<dim3(16, 12, 4), 256, 0, stream>>>(qkvb, VT, Opart, lpart);
  k_attn_comb<<<4096, 192, 0, stream>>>(Opart, lpart, attn);
  k_gemm<128, 128, 1><<<dim3(3072 / 128, 4096 / 128), 256, 0, stream>>>(
      attn, wtm1, b_m1, nullptr, act1, nullptr, nullptr, nullptr, nullptr, 0, 4096, 3072, 768);
  // second FFN GEMM: 64x64 tile, BK=128 (half the barriers at same LDS)
  k_gemm2<<<dim3(768 / 64, 4096 / 64), 256, 0, stream>>>(
      act1, wtm2, b_m2, x1, x, teacc, b_ss2, 1536, 4096, 768, 3072);

  // block 2: LN2+mod -> FFN
  k_ln_mod<<<4096, 256, 0, stream>>>(x1, ln2_g, ln2_b, teacc, b_ss2, 2304, 3072, h1);
  k_gemm<128, 128, 1><<<dim3(3072 / 128, 4096 / 128), 256, 0, stream>>>(
      h1, wtf1, b_f1, nullptr, act1, nullptr, nullptr, nullptr, nullptr, 0, 4096, 3072, 768);
  k_gemm2<<<dim3(768 / 64, 4096 / 64), 256, 0, stream>>>(
      act1, wtf2, b_f2, out, x1, teacc, b_ss2, 3840, 4096, 768, 3072);
}